// Round 4
// baseline (612.798 us; speedup 1.0000x reference)
//
#include <hip/hip_runtime.h>
#include <hip/hip_bf16.h>
#include <stdint.h>

typedef __bf16 bf16_t;
typedef bf16_t bf16x8 __attribute__((ext_vector_type(8)));
typedef float f32x4 __attribute__((ext_vector_type(4)));

#define NN 10000
#define ELLCAP 64
#define GRID 512   // 2 blocks/CU x 256 CU -- co-residency guaranteed at launch_bounds(256,2)
#define NBV 2500   // virtual gather blocks (4 nodes each)

__device__ __forceinline__ float b2f(unsigned short u) {
  union { unsigned int i; float f; } c; c.i = ((unsigned int)u) << 16; return c.f;
}
__device__ __forceinline__ unsigned short f2b(float f) {
  union { float f; unsigned int i; } c; c.f = f;
  unsigned int x = c.i;
  x += 0x7FFFu + ((x >> 16) & 1u);
  return (unsigned short)(x >> 16);
}
__device__ __forceinline__ uint4 cvt8(float4 a, float4 b) {
  uint4 r;
  r.x = (unsigned int)f2b(a.x) | ((unsigned int)f2b(a.y) << 16);
  r.y = (unsigned int)f2b(a.z) | ((unsigned int)f2b(a.w) << 16);
  r.z = (unsigned int)f2b(b.x) | ((unsigned int)f2b(b.y) << 16);
  r.w = (unsigned int)f2b(b.z) | ((unsigned int)f2b(b.w) << 16);
  return r;
}
__device__ __forceinline__ void load_lds16(const void* g, void* l) {
  __builtin_amdgcn_global_load_lds(
      (const __attribute__((address_space(1))) unsigned int*)g,
      (__attribute__((address_space(3))) unsigned int*)l, 16, 0, 0);
}
__device__ __forceinline__ f32x4 mfma16(bf16x8 a, bf16x8 b, f32x4 c) {
  return __builtin_amdgcn_mfma_f32_16x16x32_bf16(a, b, c, 0, 0, 0);
}

// ---- device-scope grid barrier (each slot used once per launch; memset zeroes slots) ----
__device__ __forceinline__ void gridbar(int* __restrict__ bar, int idx) {
  __syncthreads();
  if (threadIdx.x == 0) {
    __threadfence();   // prior global writes visible device-wide
    __hip_atomic_fetch_add(&bar[idx], 1, __ATOMIC_ACQ_REL, __HIP_MEMORY_SCOPE_AGENT);
    while (__hip_atomic_load(&bar[idx], __ATOMIC_ACQUIRE, __HIP_MEMORY_SCOPE_AGENT) < GRID)
      __builtin_amdgcn_s_sleep(1);
  }
  __syncthreads();
}

// ===== 64x128 GEMM tile, bf16 A via global_load_lds. 4 waves: wn = wave id =====
// SCALED: multiply output row r by rsqrt(1+min(cnt[r],ELLCAP)) (symmetric-norm prescale).
template <bool SCALED>
__device__ void gemm64(const unsigned short* __restrict__ A, const unsigned short* __restrict__ Bt,
                       unsigned short* __restrict__ C, const int* __restrict__ cntp,
                       int M, int Ncols, int ldc, int tm, int tn,
                       unsigned short* __restrict__ As, unsigned short* __restrict__ Bs)
{
  const int tid = threadIdx.x;
  const int lane = tid & 63;
  const int wn = tid >> 6;           // 0..3 -> 32-col slice
  const int quad = lane >> 4, l15 = lane & 15;

  const int r0 = tid >> 2, kc = tid & 3;     // r0: 0..63, kc: 0..3
  int ga = tm * 64 + r0;  if (ga > M - 1) ga = M - 1;
  const int gb0 = tn * 128 + r0;
  const int gb1 = tn * 128 + 64 + r0;
  const unsigned short* gA  = A + (size_t)ga * 512 + kc * 8;
  const unsigned short* gB0 = Bt + (size_t)gb0 * 512 + kc * 8;
  const unsigned short* gB1 = Bt + (size_t)gb1 * 512 + kc * 8;
  const int loff  = r0 * 32 + kc * 8;
  const int loff1 = (64 + r0) * 32 + kc * 8;
  const int ABUF = 64 * 32, BBUF = 128 * 32;

  f32x4 acc[4][2];
  #pragma unroll
  for (int i = 0; i < 4; i++)
    #pragma unroll
    for (int j = 0; j < 2; j++) {
      f32x4 z = {0.f, 0.f, 0.f, 0.f};
      acc[i][j] = z;
    }

  load_lds16(gA,  &As[loff]);
  load_lds16(gB0, &Bs[loff]);
  load_lds16(gB1, &Bs[loff1]);
  __syncthreads();

  for (int it = 0; it < 16; ++it) {
    const int ca = (it & 1) * ABUF, cb = (it & 1) * BBUF;
    if (it < 15) {
      const int k1 = (it + 1) * 32;
      const int na = ((it & 1) ^ 1) * ABUF, nb = ((it & 1) ^ 1) * BBUF;
      load_lds16(gA + k1,  &As[na + loff]);
      load_lds16(gB0 + k1, &Bs[nb + loff]);
      load_lds16(gB1 + k1, &Bs[nb + loff1]);
    }
    bf16x8 af[4], bfr[2];
    #pragma unroll
    for (int i = 0; i < 4; i++)
      af[i] = *(const bf16x8*)&As[ca + (i * 16 + l15) * 32 + quad * 8];
    #pragma unroll
    for (int j = 0; j < 2; j++)
      bfr[j] = *(const bf16x8*)&Bs[cb + (wn * 32 + j * 16 + l15) * 32 + quad * 8];
    #pragma unroll
    for (int i = 0; i < 4; i++)
      #pragma unroll
      for (int j = 0; j < 2; j++)
        acc[i][j] = mfma16(af[i], bfr[j], acc[i][j]);
    __syncthreads();
  }

  // C/D layout col=lane&15, row=quad*4+reg  [m89-verified]
  #pragma unroll
  for (int i = 0; i < 4; i++) {
    #pragma unroll
    for (int r = 0; r < 4; r++) {
      const int row = tm * 64 + i * 16 + quad * 4 + r;
      if (row < M) {
        float dv = 1.f;
        if (SCALED) {
          int c = cntp[row]; if (c > ELLCAP) c = ELLCAP;
          dv = rsqrtf((float)(1 + c));
        }
        #pragma unroll
        for (int j = 0; j < 2; j++) {
          const int col = tn * 128 + wn * 32 + j * 16 + l15;
          if (col < Ncols)
            C[(size_t)row * ldc + col] = f2b(acc[i][j][r] * dv);
        }
      }
    }
  }
}

// ---- LDS-tiled 64x64 transpose: W fp32 [512][ncols] -> Wt bf16 [.][512] ----
__device__ void wtrans_tile(const float* __restrict__ W, unsigned short* __restrict__ Wt,
                            int ncols, int tr0, int tc0, float (*tile)[65])
{
  const int t = threadIdx.x;
  const int r = t >> 2, c4 = t & 3;
  #pragma unroll
  for (int i = 0; i < 4; i++) {
    int col = c4 * 16 + i * 4;
    int gc = tc0 + col;
    float4 v;
    if (gc + 3 < ncols) {
      v = *(const float4*)&W[(size_t)(tr0 + r) * ncols + gc];
    } else {
      v.x = (gc + 0 < ncols) ? W[(size_t)(tr0 + r) * ncols + gc + 0] : 0.f;
      v.y = (gc + 1 < ncols) ? W[(size_t)(tr0 + r) * ncols + gc + 1] : 0.f;
      v.z = (gc + 2 < ncols) ? W[(size_t)(tr0 + r) * ncols + gc + 2] : 0.f;
      v.w = (gc + 3 < ncols) ? W[(size_t)(tr0 + r) * ncols + gc + 3] : 0.f;
    }
    tile[r][col] = v.x; tile[r][col + 1] = v.y;
    tile[r][col + 2] = v.z; tile[r][col + 3] = v.w;
  }
  __syncthreads();
  const int o = t >> 2;
  #pragma unroll
  for (int i = 0; i < 4; i++) {
    int k = c4 * 16 + i * 4;
    ushort4 u;
    u.x = f2b(tile[k + 0][o]); u.y = f2b(tile[k + 1][o]);
    u.z = f2b(tile[k + 2][o]); u.w = f2b(tile[k + 3][o]);
    *(ushort4*)&Wt[(size_t)(tc0 + o) * 512 + tr0 + k] = u;
  }
  __syncthreads();   // smem reused by caller afterwards
}

// ---- phase-0 streaming work (W2->bf16, x->bf16, ELL build) ----
__device__ void prep_stream(int b, int nstream, const float* __restrict__ W2,
                            const float* __restrict__ x, const int* __restrict__ src,
                            const int* __restrict__ dst, int* __restrict__ cnt,
                            int* __restrict__ ell, unsigned short* __restrict__ w2b,
                            unsigned short* __restrict__ xb, int E)
{
  const int t0 = b * 256 + threadIdx.x;
  const int FT = nstream * 256;
  const float4* W24 = (const float4*)W2;
  uint4* w2b4 = (uint4*)w2b;
  for (int i = t0; i < 512 * 512 / 8; i += FT)
    w2b4[i] = cvt8(W24[i * 2], W24[i * 2 + 1]);
  const float4* x4 = (const float4*)x;
  uint4* xb4 = (uint4*)xb;
  for (int i = t0; i < NN * 512 / 8; i += FT)
    xb4[i] = cvt8(x4[i * 2], x4[i * 2 + 1]);
  for (int e = t0; e < E; e += FT) {
    int s = src[e], d = dst[e];
    int pos = atomicAdd(&cnt[d], 1);
    if (pos < ELLCAP) ell[d * ELLCAP + pos] = s;   // P(overflow) ~ 1e-18 @ Poisson(16)
  }
}

// ---- bias2c = bc + b2 @ Wc (one block, 100 lanes) ----
__device__ void bias_fold(const float* __restrict__ b2, const float* __restrict__ Wc,
                          const float* __restrict__ bc, float* __restrict__ bias2c)
{
  const int j = threadIdx.x;
  if (j < 128) {
    float s = 0.f;
    if (j < 100) {
      s = bc[j];
      for (int k = 0; k < 512; k++) s = fmaf(b2[k], Wc[k * 100 + j], s);
    }
    bias2c[j] = s;
  }
}

// ---- gather1 body: 4 nodes per virtual block, full 512-col rows, 16B/lane ----
__device__ __forceinline__ void add8(float* a, uint4 v) {
  a[0] += b2f((unsigned short)(v.x & 0xffffu));
  a[1] += b2f((unsigned short)(v.x >> 16));
  a[2] += b2f((unsigned short)(v.y & 0xffffu));
  a[3] += b2f((unsigned short)(v.y >> 16));
  a[4] += b2f((unsigned short)(v.z & 0xffffu));
  a[5] += b2f((unsigned short)(v.z >> 16));
  a[6] += b2f((unsigned short)(v.w & 0xffffu));
  a[7] += b2f((unsigned short)(v.w >> 16));
}

__device__ void gather1_body(int vb, const unsigned short* __restrict__ h,
                             const int* __restrict__ cnt, const int* __restrict__ ell,
                             const float* __restrict__ bias, unsigned short* __restrict__ outb)
{
  int node = vb * 4 + (threadIdx.x >> 6);
  if (node >= NN) return;
  const int lane = threadIdx.x & 63;
  const int c8 = lane * 8;

  int cd = cnt[node]; if (cd > ELLCAP) cd = ELLCAP;
  const float dinv = rsqrtf((float)(1 + cd));
  uint4 hv = *(const uint4*)&h[(size_t)node * 512 + c8];
  float a[8] = {0.f, 0.f, 0.f, 0.f, 0.f, 0.f, 0.f, 0.f};
  add8(a, hv);                     // self term B2'[d]

  const int* row = ell + node * ELLCAP;
  int j = 0;
  for (; j + 8 <= cd; j += 8) {
    int ss[8]; uint4 vv[8];
    #pragma unroll
    for (int q = 0; q < 8; q++) ss[q] = row[j + q];
    #pragma unroll
    for (int q = 0; q < 8; q++) vv[q] = *(const uint4*)&h[(size_t)ss[q] * 512 + c8];
    #pragma unroll
    for (int q = 0; q < 8; q++) add8(a, vv[q]);
  }
  for (; j < cd; ++j) {
    int s = row[j];
    uint4 v = *(const uint4*)&h[(size_t)s * 512 + c8];
    add8(a, v);
  }

  const float4* bp = (const float4*)&bias[c8];
  float4 b0 = bp[0], b1 = bp[1];
  float bb[8] = {b0.x, b0.y, b0.z, b0.w, b1.x, b1.y, b1.z, b1.w};
  #pragma unroll
  for (int q = 0; q < 8; q++) a[q] = fmaxf(fmaf(a[q], dinv, bb[q]), 0.f);
  uint4 o;
  o.x = (unsigned int)f2b(a[0]) | ((unsigned int)f2b(a[1]) << 16);
  o.y = (unsigned int)f2b(a[2]) | ((unsigned int)f2b(a[3]) << 16);
  o.z = (unsigned int)f2b(a[4]) | ((unsigned int)f2b(a[5]) << 16);
  o.w = (unsigned int)f2b(a[6]) | ((unsigned int)f2b(a[7]) << 16);
  *(uint4*)&outb[(size_t)node * 512 + c8] = o;
}

// ---- gather2c body: 4 nodes per virtual block, 128-col bf16 Z rows ----
__device__ void gather2c_body(int vb, const unsigned short* __restrict__ Z,
                              const int* __restrict__ cnt, const int* __restrict__ ell,
                              const float* __restrict__ bias2c, float* __restrict__ out)
{
  int node = vb * 4 + (threadIdx.x >> 6);
  if (node >= NN) return;
  const int lane = threadIdx.x & 63;
  const int c2 = lane * 2;

  int cd = cnt[node]; if (cd > ELLCAP) cd = ELLCAP;
  const float dinv = rsqrtf((float)(1 + cd));
  unsigned int hv = *(const unsigned int*)&Z[(size_t)node * 128 + c2];
  float a0 = b2f((unsigned short)(hv & 0xffffu));
  float a1 = b2f((unsigned short)(hv >> 16));

  const int* row = ell + node * ELLCAP;
  int j = 0;
  for (; j + 8 <= cd; j += 8) {
    int ss[8]; unsigned int vv[8];
    #pragma unroll
    for (int q = 0; q < 8; q++) ss[q] = row[j + q];
    #pragma unroll
    for (int q = 0; q < 8; q++) vv[q] = *(const unsigned int*)&Z[(size_t)ss[q] * 128 + c2];
    #pragma unroll
    for (int q = 0; q < 8; q++) {
      a0 += b2f((unsigned short)(vv[q] & 0xffffu));
      a1 += b2f((unsigned short)(vv[q] >> 16));
    }
  }
  for (; j < cd; ++j) {
    int s = row[j];
    unsigned int v = *(const unsigned int*)&Z[(size_t)s * 128 + c2];
    a0 += b2f((unsigned short)(v & 0xffffu));
    a1 += b2f((unsigned short)(v >> 16));
  }
  if (c2 < 100) {
    const float2 bb = *(const float2*)&bias2c[c2];
    *(float2*)&out[(size_t)node * 100 + c2] =
        make_float2(fmaf(a0, dinv, bb.x), fmaf(a1, dinv, bb.y));
  }
}

// ================= fused persistent kernel (manual grid barrier) =================
__global__ __launch_bounds__(256, 2)
void fused(const float* __restrict__ x, const int* __restrict__ src, const int* __restrict__ dst,
           const float* __restrict__ W1, const float* __restrict__ b1,
           const float* __restrict__ W2, const float* __restrict__ b2,
           const float* __restrict__ Wc, const float* __restrict__ bc,
           float* __restrict__ out, int* __restrict__ bar, int* __restrict__ cnt,
           int* __restrict__ ell, float* __restrict__ bias2c,
           unsigned short* __restrict__ W1t, unsigned short* __restrict__ Wct,
           unsigned short* __restrict__ w2b, unsigned short* __restrict__ W2WcT,
           unsigned short* __restrict__ B1, unsigned short* __restrict__ B2,
           unsigned short* __restrict__ Z, unsigned short* __restrict__ xb, int E)
{
  __shared__ __align__(16) unsigned char smem[24576];
  unsigned short* As = (unsigned short*)smem;
  unsigned short* Bs = (unsigned short*)(smem + 8192);
  const int b = blockIdx.x;

  // phase 0: weight prep + x->bf16 + ELL build
  if (b < 64)      wtrans_tile(W1, W1t, 512, (b >> 3) * 64, (b & 7) * 64, (float(*)[65])smem);
  else if (b < 80) { int t = b - 64; wtrans_tile(Wc, Wct, 100, (t >> 1) * 64, (t & 1) * 64, (float(*)[65])smem); }
  else             prep_stream(b - 80, GRID - 80, W2, x, src, dst, cnt, ell, w2b, xb, E);
  gridbar(bar, 0);

  // phase 1: gemm1 (628 tiles, dinv-prescaled) + W2Wc fold (8 tiles) + bias2c
  for (int t = b; t < 637; t += GRID) {
    if (t < 628)      gemm64<true>(xb, W1t, B2, cnt, NN, 512, 512, t >> 2, t & 3, As, Bs);
    else if (t < 636) { int g = t - 628; gemm64<false>(Wct, w2b, W2WcT, nullptr, 128, 512, 512, g >> 2, g & 3, As, Bs); }
    else              bias_fold(b2, Wc, bc, bias2c);
  }
  gridbar(bar, 1);

  // phase 2: gather1 -> B1 (relu'd H1 in bf16)
  for (int vb = b; vb < NBV; vb += GRID) gather1_body(vb, B2, cnt, ell, b1, B1);
  gridbar(bar, 2);

  // phase 3: gemm2c -> Z (dinv-prescaled)
  if (b < 157) gemm64<true>(B1, W2WcT, Z, cnt, NN, 128, 128, b, 0, As, Bs);
  gridbar(bar, 3);

  // phase 4: gather2c -> out
  for (int vb = b; vb < NBV; vb += GRID) gather2c_body(vb, Z, cnt, ell, bias2c, out);
}

extern "C" void kernel_launch(void* const* d_in, const int* in_sizes, int n_in,
                              void* d_out, int out_size, void* d_ws, size_t ws_size,
                              hipStream_t stream) {
  const float* x  = (const float*)d_in[0];
  const int*   ei = (const int*)d_in[1];
  const float* W1 = (const float*)d_in[2];
  const float* b1 = (const float*)d_in[3];
  const float* W2 = (const float*)d_in[4];
  const float* b2 = (const float*)d_in[5];
  const float* Wc = (const float*)d_in[6];
  const float* bc = (const float*)d_in[7];
  float* out = (float*)d_out;

  const int n = NN;
  int E = in_sizes[1] / 2;
  const int* src = ei;
  const int* dst = ei + E;

  // workspace (~28 MB)
  char* w = (char*)d_ws;
  int* bar = (int*)w;                       w += 256;   // 4 barrier slots (zeroed each launch)
  int* cnt = (int*)w;                       w += ((n * 4 + 255) / 256) * 256;
  int* ell = (int*)w;                       w += ((n * ELLCAP * 4 + 255) / 256) * 256;
  float* bias2c = (float*)w;                w += 512;
  unsigned short* W1t = (unsigned short*)w; w += 512 * 512 * 2;
  unsigned short* Wct = (unsigned short*)w; w += 128 * 512 * 2;
  unsigned short* w2b = (unsigned short*)w; w += 512 * 512 * 2;
  unsigned short* W2WcT = (unsigned short*)w; w += 128 * 512 * 2;
  unsigned short* B1  = (unsigned short*)w; w += (size_t)n * 512 * 2;
  unsigned short* B2  = (unsigned short*)w; w += (size_t)n * 512 * 2;
  unsigned short* Z   = (unsigned short*)w; w += (size_t)n * 128 * 2;

  // xb (bf16 x) aliases B1: xb dies after phase 1, B1 is born in phase 2.
  unsigned short* xb = B1;

  // zero bar + cnt in one memset (graph replay re-runs this each iteration)
  hipMemsetAsync(bar, 0, 256 + ((n * 4 + 255) / 256) * 256, stream);

  void* args[] = {(void*)&x, (void*)&src, (void*)&dst, (void*)&W1, (void*)&b1,
                  (void*)&W2, (void*)&b2, (void*)&Wc, (void*)&bc, (void*)&out,
                  (void*)&bar, (void*)&cnt, (void*)&ell, (void*)&bias2c,
                  (void*)&W1t, (void*)&Wct, (void*)&w2b, (void*)&W2WcT,
                  (void*)&B1, (void*)&B2, (void*)&Z, (void*)&xb, (void*)&E};
  hipLaunchKernel((const void*)fused, dim3(GRID), dim3(256), args, 0, stream);
}

// Round 5
// 524.009 us; speedup vs baseline: 1.1694x; 1.1694x over previous
//
#include <hip/hip_runtime.h>
#include <hip/hip_bf16.h>
#include <stdint.h>

typedef __bf16 bf16_t;
typedef bf16_t bf16x8 __attribute__((ext_vector_type(8)));
typedef float f32x4 __attribute__((ext_vector_type(4)));

#define NN 10000
#define ELLCAP 64
#define GRID 512   // 2 blocks/CU x 256 CU -- co-residency guaranteed at launch_bounds(256,2)
#define NBV 2500   // virtual gather blocks (4 nodes each)

__device__ __forceinline__ float b2f(unsigned short u) {
  union { unsigned int i; float f; } c; c.i = ((unsigned int)u) << 16; return c.f;
}
__device__ __forceinline__ unsigned short f2b(float f) {
  union { float f; unsigned int i; } c; c.f = f;
  unsigned int x = c.i;
  x += 0x7FFFu + ((x >> 16) & 1u);
  return (unsigned short)(x >> 16);
}
__device__ __forceinline__ uint4 cvt8(float4 a, float4 b) {
  uint4 r;
  r.x = (unsigned int)f2b(a.x) | ((unsigned int)f2b(a.y) << 16);
  r.y = (unsigned int)f2b(a.z) | ((unsigned int)f2b(a.w) << 16);
  r.z = (unsigned int)f2b(b.x) | ((unsigned int)f2b(b.y) << 16);
  r.w = (unsigned int)f2b(b.z) | ((unsigned int)f2b(b.w) << 16);
  return r;
}
__device__ __forceinline__ void load_lds16(const void* g, void* l) {
  __builtin_amdgcn_global_load_lds(
      (const __attribute__((address_space(1))) unsigned int*)g,
      (__attribute__((address_space(3))) unsigned int*)l, 16, 0, 0);
}
__device__ __forceinline__ f32x4 mfma16(bf16x8 a, bf16x8 b, f32x4 c) {
  return __builtin_amdgcn_mfma_f32_16x16x32_bf16(a, b, c, 0, 0, 0);
}

// ---- device-scope grid barrier with exponential-backoff polling ----
// R4 lesson: s_sleep(1) polling by ~511 blocks on one cacheline saturates the
// coherence fabric (532us, all pipes idle). Backoff to ~3.4us poll period.
__device__ __forceinline__ void gridbar(int* __restrict__ bar, int idx) {
  __syncthreads();
  if (threadIdx.x == 0) {
    __threadfence();   // prior global writes visible device-wide
    int arrived = __hip_atomic_fetch_add(&bar[idx], 1, __ATOMIC_ACQ_REL,
                                         __HIP_MEMORY_SCOPE_AGENT) + 1;
    if (arrived < GRID) {
      int it = 0;
      while (__hip_atomic_load(&bar[idx], __ATOMIC_ACQUIRE,
                               __HIP_MEMORY_SCOPE_AGENT) < GRID) {
        if (it < 2)      __builtin_amdgcn_s_sleep(2);    // ~0.05us
        else if (it < 4) __builtin_amdgcn_s_sleep(8);    // ~0.2us
        else if (it < 6) __builtin_amdgcn_s_sleep(32);   // ~0.85us
        else             __builtin_amdgcn_s_sleep(127);  // ~3.4us steady state
        ++it;
      }
    }
  }
  __syncthreads();
}

// ===== 64x128 GEMM tile, bf16 A via global_load_lds. 4 waves: wn = wave id =====
// SCALED: multiply output row r by rsqrt(1+min(cnt[r],ELLCAP)) (symmetric-norm prescale).
template <bool SCALED>
__device__ void gemm64(const unsigned short* __restrict__ A, const unsigned short* __restrict__ Bt,
                       unsigned short* __restrict__ C, const int* __restrict__ cntp,
                       int M, int Ncols, int ldc, int tm, int tn,
                       unsigned short* __restrict__ As, unsigned short* __restrict__ Bs)
{
  const int tid = threadIdx.x;
  const int lane = tid & 63;
  const int wn = tid >> 6;           // 0..3 -> 32-col slice
  const int quad = lane >> 4, l15 = lane & 15;

  const int r0 = tid >> 2, kc = tid & 3;     // r0: 0..63, kc: 0..3
  int ga = tm * 64 + r0;  if (ga > M - 1) ga = M - 1;
  const int gb0 = tn * 128 + r0;
  const int gb1 = tn * 128 + 64 + r0;
  const unsigned short* gA  = A + (size_t)ga * 512 + kc * 8;
  const unsigned short* gB0 = Bt + (size_t)gb0 * 512 + kc * 8;
  const unsigned short* gB1 = Bt + (size_t)gb1 * 512 + kc * 8;
  const int loff  = r0 * 32 + kc * 8;
  const int loff1 = (64 + r0) * 32 + kc * 8;
  const int ABUF = 64 * 32, BBUF = 128 * 32;

  f32x4 acc[4][2];
  #pragma unroll
  for (int i = 0; i < 4; i++)
    #pragma unroll
    for (int j = 0; j < 2; j++) {
      f32x4 z = {0.f, 0.f, 0.f, 0.f};
      acc[i][j] = z;
    }

  load_lds16(gA,  &As[loff]);
  load_lds16(gB0, &Bs[loff]);
  load_lds16(gB1, &Bs[loff1]);
  __syncthreads();

  for (int it = 0; it < 16; ++it) {
    const int ca = (it & 1) * ABUF, cb = (it & 1) * BBUF;
    if (it < 15) {
      const int k1 = (it + 1) * 32;
      const int na = ((it & 1) ^ 1) * ABUF, nb = ((it & 1) ^ 1) * BBUF;
      load_lds16(gA + k1,  &As[na + loff]);
      load_lds16(gB0 + k1, &Bs[nb + loff]);
      load_lds16(gB1 + k1, &Bs[nb + loff1]);
    }
    bf16x8 af[4], bfr[2];
    #pragma unroll
    for (int i = 0; i < 4; i++)
      af[i] = *(const bf16x8*)&As[ca + (i * 16 + l15) * 32 + quad * 8];
    #pragma unroll
    for (int j = 0; j < 2; j++)
      bfr[j] = *(const bf16x8*)&Bs[cb + (wn * 32 + j * 16 + l15) * 32 + quad * 8];
    #pragma unroll
    for (int i = 0; i < 4; i++)
      #pragma unroll
      for (int j = 0; j < 2; j++)
        acc[i][j] = mfma16(af[i], bfr[j], acc[i][j]);
    __syncthreads();
  }

  // C/D layout col=lane&15, row=quad*4+reg  [m89-verified]
  #pragma unroll
  for (int i = 0; i < 4; i++) {
    #pragma unroll
    for (int r = 0; r < 4; r++) {
      const int row = tm * 64 + i * 16 + quad * 4 + r;
      if (row < M) {
        float dv = 1.f;
        if (SCALED) {
          int c = cntp[row]; if (c > ELLCAP) c = ELLCAP;
          dv = rsqrtf((float)(1 + c));
        }
        #pragma unroll
        for (int j = 0; j < 2; j++) {
          const int col = tn * 128 + wn * 32 + j * 16 + l15;
          if (col < Ncols)
            C[(size_t)row * ldc + col] = f2b(acc[i][j][r] * dv);
        }
      }
    }
  }
}

// ---- LDS-tiled 64x64 transpose: W fp32 [512][ncols] -> Wt bf16 [.][512] ----
__device__ void wtrans_tile(const float* __restrict__ W, unsigned short* __restrict__ Wt,
                            int ncols, int tr0, int tc0, float (*tile)[65])
{
  const int t = threadIdx.x;
  const int r = t >> 2, c4 = t & 3;
  #pragma unroll
  for (int i = 0; i < 4; i++) {
    int col = c4 * 16 + i * 4;
    int gc = tc0 + col;
    float4 v;
    if (gc + 3 < ncols) {
      v = *(const float4*)&W[(size_t)(tr0 + r) * ncols + gc];
    } else {
      v.x = (gc + 0 < ncols) ? W[(size_t)(tr0 + r) * ncols + gc + 0] : 0.f;
      v.y = (gc + 1 < ncols) ? W[(size_t)(tr0 + r) * ncols + gc + 1] : 0.f;
      v.z = (gc + 2 < ncols) ? W[(size_t)(tr0 + r) * ncols + gc + 2] : 0.f;
      v.w = (gc + 3 < ncols) ? W[(size_t)(tr0 + r) * ncols + gc + 3] : 0.f;
    }
    tile[r][col] = v.x; tile[r][col + 1] = v.y;
    tile[r][col + 2] = v.z; tile[r][col + 3] = v.w;
  }
  __syncthreads();
  const int o = t >> 2;
  #pragma unroll
  for (int i = 0; i < 4; i++) {
    int k = c4 * 16 + i * 4;
    ushort4 u;
    u.x = f2b(tile[k + 0][o]); u.y = f2b(tile[k + 1][o]);
    u.z = f2b(tile[k + 2][o]); u.w = f2b(tile[k + 3][o]);
    *(ushort4*)&Wt[(size_t)(tc0 + o) * 512 + tr0 + k] = u;
  }
  __syncthreads();   // smem reused by caller afterwards
}

// ---- phase-0 streaming work (W2->bf16, x->bf16, ELL build) ----
__device__ void prep_stream(int b, int nstream, const float* __restrict__ W2,
                            const float* __restrict__ x, const int* __restrict__ src,
                            const int* __restrict__ dst, int* __restrict__ cnt,
                            int* __restrict__ ell, unsigned short* __restrict__ w2b,
                            unsigned short* __restrict__ xb, int E)
{
  const int t0 = b * 256 + threadIdx.x;
  const int FT = nstream * 256;
  const float4* W24 = (const float4*)W2;
  uint4* w2b4 = (uint4*)w2b;
  for (int i = t0; i < 512 * 512 / 8; i += FT)
    w2b4[i] = cvt8(W24[i * 2], W24[i * 2 + 1]);
  const float4* x4 = (const float4*)x;
  uint4* xb4 = (uint4*)xb;
  for (int i = t0; i < NN * 512 / 8; i += FT)
    xb4[i] = cvt8(x4[i * 2], x4[i * 2 + 1]);
  for (int e = t0; e < E; e += FT) {
    int s = src[e], d = dst[e];
    int pos = atomicAdd(&cnt[d], 1);
    if (pos < ELLCAP) ell[d * ELLCAP + pos] = s;   // P(overflow) ~ 1e-18 @ Poisson(16)
  }
}

// ---- bias2c = bc + b2 @ Wc (one block, 100 lanes; depends only on INPUTS) ----
__device__ void bias_fold(const float* __restrict__ b2, const float* __restrict__ Wc,
                          const float* __restrict__ bc, float* __restrict__ bias2c)
{
  const int j = threadIdx.x;
  if (j < 128) {
    float s = 0.f;
    if (j < 100) {
      s = bc[j];
      for (int k = 0; k < 512; k++) s = fmaf(b2[k], Wc[k * 100 + j], s);
    }
    bias2c[j] = s;
  }
}

// ---- gather1 body: 4 nodes per virtual block, full 512-col rows, 16B/lane ----
__device__ __forceinline__ void add8(float* a, uint4 v) {
  a[0] += b2f((unsigned short)(v.x & 0xffffu));
  a[1] += b2f((unsigned short)(v.x >> 16));
  a[2] += b2f((unsigned short)(v.y & 0xffffu));
  a[3] += b2f((unsigned short)(v.y >> 16));
  a[4] += b2f((unsigned short)(v.z & 0xffffu));
  a[5] += b2f((unsigned short)(v.z >> 16));
  a[6] += b2f((unsigned short)(v.w & 0xffffu));
  a[7] += b2f((unsigned short)(v.w >> 16));
}

__device__ void gather1_body(int vb, const unsigned short* __restrict__ h,
                             const int* __restrict__ cnt, const int* __restrict__ ell,
                             const float* __restrict__ bias, unsigned short* __restrict__ outb)
{
  int node = vb * 4 + (threadIdx.x >> 6);
  if (node >= NN) return;
  const int lane = threadIdx.x & 63;
  const int c8 = lane * 8;

  int cd = cnt[node]; if (cd > ELLCAP) cd = ELLCAP;
  const float dinv = rsqrtf((float)(1 + cd));
  uint4 hv = *(const uint4*)&h[(size_t)node * 512 + c8];
  float a[8] = {0.f, 0.f, 0.f, 0.f, 0.f, 0.f, 0.f, 0.f};
  add8(a, hv);                     // self term B2'[d]

  const int* row = ell + node * ELLCAP;
  int j = 0;
  for (; j + 8 <= cd; j += 8) {
    int ss[8]; uint4 vv[8];
    #pragma unroll
    for (int q = 0; q < 8; q++) ss[q] = row[j + q];
    #pragma unroll
    for (int q = 0; q < 8; q++) vv[q] = *(const uint4*)&h[(size_t)ss[q] * 512 + c8];
    #pragma unroll
    for (int q = 0; q < 8; q++) add8(a, vv[q]);
  }
  for (; j < cd; ++j) {
    int s = row[j];
    uint4 v = *(const uint4*)&h[(size_t)s * 512 + c8];
    add8(a, v);
  }

  const float4* bp = (const float4*)&bias[c8];
  float4 b0 = bp[0], b1 = bp[1];
  float bb[8] = {b0.x, b0.y, b0.z, b0.w, b1.x, b1.y, b1.z, b1.w};
  #pragma unroll
  for (int q = 0; q < 8; q++) a[q] = fmaxf(fmaf(a[q], dinv, bb[q]), 0.f);
  uint4 o;
  o.x = (unsigned int)f2b(a[0]) | ((unsigned int)f2b(a[1]) << 16);
  o.y = (unsigned int)f2b(a[2]) | ((unsigned int)f2b(a[3]) << 16);
  o.z = (unsigned int)f2b(a[4]) | ((unsigned int)f2b(a[5]) << 16);
  o.w = (unsigned int)f2b(a[6]) | ((unsigned int)f2b(a[7]) << 16);
  *(uint4*)&outb[(size_t)node * 512 + c8] = o;
}

// ---- gather2c body: 4 nodes per virtual block, 128-col bf16 Z rows ----
__device__ void gather2c_body(int vb, const unsigned short* __restrict__ Z,
                              const int* __restrict__ cnt, const int* __restrict__ ell,
                              const float* __restrict__ bias2c, float* __restrict__ out)
{
  int node = vb * 4 + (threadIdx.x >> 6);
  if (node >= NN) return;
  const int lane = threadIdx.x & 63;
  const int c2 = lane * 2;

  int cd = cnt[node]; if (cd > ELLCAP) cd = ELLCAP;
  const float dinv = rsqrtf((float)(1 + cd));
  unsigned int hv = *(const unsigned int*)&Z[(size_t)node * 128 + c2];
  float a0 = b2f((unsigned short)(hv & 0xffffu));
  float a1 = b2f((unsigned short)(hv >> 16));

  const int* row = ell + node * ELLCAP;
  int j = 0;
  for (; j + 8 <= cd; j += 8) {
    int ss[8]; unsigned int vv[8];
    #pragma unroll
    for (int q = 0; q < 8; q++) ss[q] = row[j + q];
    #pragma unroll
    for (int q = 0; q < 8; q++) vv[q] = *(const unsigned int*)&Z[(size_t)ss[q] * 128 + c2];
    #pragma unroll
    for (int q = 0; q < 8; q++) {
      a0 += b2f((unsigned short)(vv[q] & 0xffffu));
      a1 += b2f((unsigned short)(vv[q] >> 16));
    }
  }
  for (; j < cd; ++j) {
    int s = row[j];
    unsigned int v = *(const unsigned int*)&Z[(size_t)s * 128 + c2];
    a0 += b2f((unsigned short)(v & 0xffffu));
    a1 += b2f((unsigned short)(v >> 16));
  }
  if (c2 < 100) {
    const float2 bb = *(const float2*)&bias2c[c2];
    *(float2*)&out[(size_t)node * 100 + c2] =
        make_float2(fmaf(a0, dinv, bb.x), fmaf(a1, dinv, bb.y));
  }
}

// ================= fused persistent kernel (manual grid barrier) =================
__global__ __launch_bounds__(256, 2)
void fused(const float* __restrict__ x, const int* __restrict__ src, const int* __restrict__ dst,
           const float* __restrict__ W1, const float* __restrict__ b1,
           const float* __restrict__ W2, const float* __restrict__ b2,
           const float* __restrict__ Wc, const float* __restrict__ bc,
           float* __restrict__ out, int* __restrict__ bar, int* __restrict__ cnt,
           int* __restrict__ ell, float* __restrict__ bias2c,
           unsigned short* __restrict__ W1t, unsigned short* __restrict__ Wct,
           unsigned short* __restrict__ w2b, unsigned short* __restrict__ W2WcT,
           unsigned short* __restrict__ B1, unsigned short* __restrict__ B2,
           unsigned short* __restrict__ Z, unsigned short* __restrict__ xb, int E)
{
  __shared__ __align__(16) unsigned char smem[24576];
  unsigned short* As = (unsigned short*)smem;
  unsigned short* Bs = (unsigned short*)(smem + 8192);
  const int b = blockIdx.x;

  // phase 0: weight prep + bias fold + x->bf16 + ELL build
  if (b < 64)       wtrans_tile(W1, W1t, 512, (b >> 3) * 64, (b & 7) * 64, (float(*)[65])smem);
  else if (b < 80)  { int t = b - 64; wtrans_tile(Wc, Wct, 100, (t >> 1) * 64, (t & 1) * 64, (float(*)[65])smem); }
  else if (b == 80) bias_fold(b2, Wc, bc, bias2c);
  else              prep_stream(b - 81, GRID - 81, W2, x, src, dst, cnt, ell, w2b, xb, E);
  gridbar(bar, 0);

  // phase 1: gemm1 (628 tiles, dinv-prescaled) + W2Wc fold (8 tiles)
  for (int t = b; t < 636; t += GRID) {
    if (t < 628)  gemm64<true>(xb, W1t, B2, cnt, NN, 512, 512, t >> 2, t & 3, As, Bs);
    else          { int g = t - 628; gemm64<false>(Wct, w2b, W2WcT, nullptr, 128, 512, 512, g >> 2, g & 3, As, Bs); }
  }
  gridbar(bar, 1);

  // phase 2: gather1 -> B1 (relu'd H1 in bf16)
  for (int vb = b; vb < NBV; vb += GRID) gather1_body(vb, B2, cnt, ell, b1, B1);
  gridbar(bar, 2);

  // phase 3: gemm2c -> Z (dinv-prescaled)
  if (b < 157) gemm64<true>(B1, W2WcT, Z, cnt, NN, 128, 128, b, 0, As, Bs);
  gridbar(bar, 3);

  // phase 4: gather2c -> out
  for (int vb = b; vb < NBV; vb += GRID) gather2c_body(vb, Z, cnt, ell, bias2c, out);
}

extern "C" void kernel_launch(void* const* d_in, const int* in_sizes, int n_in,
                              void* d_out, int out_size, void* d_ws, size_t ws_size,
                              hipStream_t stream) {
  const float* x  = (const float*)d_in[0];
  const int*   ei = (const int*)d_in[1];
  const float* W1 = (const float*)d_in[2];
  const float* b1 = (const float*)d_in[3];
  const float* W2 = (const float*)d_in[4];
  const float* b2 = (const float*)d_in[5];
  const float* Wc = (const float*)d_in[6];
  const float* bc = (const float*)d_in[7];
  float* out = (float*)d_out;

  const int n = NN;
  int E = in_sizes[1] / 2;
  const int* src = ei;
  const int* dst = ei + E;

  // workspace (~28 MB)
  char* w = (char*)d_ws;
  int* bar = (int*)w;                       w += 256;   // 4 barrier slots (zeroed each launch)
  int* cnt = (int*)w;                       w += ((n * 4 + 255) / 256) * 256;
  int* ell = (int*)w;                       w += ((n * ELLCAP * 4 + 255) / 256) * 256;
  float* bias2c = (float*)w;                w += 512;
  unsigned short* W1t = (unsigned short*)w; w += 512 * 512 * 2;
  unsigned short* Wct = (unsigned short*)w; w += 128 * 512 * 2;
  unsigned short* w2b = (unsigned short*)w; w += 512 * 512 * 2;
  unsigned short* W2WcT = (unsigned short*)w; w += 128 * 512 * 2;
  unsigned short* B1  = (unsigned short*)w; w += (size_t)n * 512 * 2;
  unsigned short* B2  = (unsigned short*)w; w += (size_t)n * 512 * 2;
  unsigned short* Z   = (unsigned short*)w; w += (size_t)n * 128 * 2;

  // xb (bf16 x) aliases B1: xb dies after phase 1, B1 is born in phase 2.
  unsigned short* xb = B1;

  // zero bar + cnt in one memset (graph replay re-runs this each iteration)
  hipMemsetAsync(bar, 0, 256 + ((n * 4 + 255) / 256) * 256, stream);

  void* args[] = {(void*)&x, (void*)&src, (void*)&dst, (void*)&W1, (void*)&b1,
                  (void*)&W2, (void*)&b2, (void*)&Wc, (void*)&bc, (void*)&out,
                  (void*)&bar, (void*)&cnt, (void*)&ell, (void*)&bias2c,
                  (void*)&W1t, (void*)&Wct, (void*)&w2b, (void*)&W2WcT,
                  (void*)&B1, (void*)&B2, (void*)&Z, (void*)&xb, (void*)&E};
  hipLaunchKernel((const void*)fused, dim3(GRID), dim3(256), args, 0, stream);
}

// Round 6
// 156.858 us; speedup vs baseline: 3.9067x; 3.3407x over previous
//
#include <hip/hip_runtime.h>
#include <hip/hip_bf16.h>
#include <stdint.h>

typedef __bf16 bf16_t;
typedef bf16_t bf16x8 __attribute__((ext_vector_type(8)));
typedef float f32x4 __attribute__((ext_vector_type(4)));

#define NN 10000
#define ELLCAP 64

__device__ __forceinline__ float b2f(unsigned short u) {
  union { unsigned int i; float f; } c; c.i = ((unsigned int)u) << 16; return c.f;
}
__device__ __forceinline__ unsigned short f2b(float f) {
  union { float f; unsigned int i; } c; c.f = f;
  unsigned int x = c.i;
  x += 0x7FFFu + ((x >> 16) & 1u);
  return (unsigned short)(x >> 16);
}
__device__ __forceinline__ uint4 cvt8(float4 a, float4 b) {
  uint4 r;
  r.x = (unsigned int)f2b(a.x) | ((unsigned int)f2b(a.y) << 16);
  r.y = (unsigned int)f2b(a.z) | ((unsigned int)f2b(a.w) << 16);
  r.z = (unsigned int)f2b(b.x) | ((unsigned int)f2b(b.y) << 16);
  r.w = (unsigned int)f2b(b.z) | ((unsigned int)f2b(b.w) << 16);
  return r;
}
__device__ __forceinline__ void load_lds16(const void* g, void* l) {
  __builtin_amdgcn_global_load_lds(
      (const __attribute__((address_space(1))) unsigned int*)g,
      (__attribute__((address_space(3))) unsigned int*)l, 16, 0, 0);
}
__device__ __forceinline__ f32x4 mfma16(bf16x8 a, bf16x8 b, f32x4 c) {
  return __builtin_amdgcn_mfma_f32_16x16x32_bf16(a, b, c, 0, 0, 0);
}

// ===== 64x128 GEMM tile, bf16 A via global_load_lds. 4 waves: wn = wave id =====
// SCALED: multiply output row r by rsqrt(1+min(cnt[r],ELLCAP)) (symmetric-norm prescale).
template <bool SCALED>
__device__ void gemm64(const unsigned short* __restrict__ A, const unsigned short* __restrict__ Bt,
                       unsigned short* __restrict__ C, const int* __restrict__ cntp,
                       int M, int Ncols, int ldc, int tm, int tn,
                       unsigned short* __restrict__ As, unsigned short* __restrict__ Bs)
{
  const int tid = threadIdx.x;
  const int lane = tid & 63;
  const int wn = tid >> 6;           // 0..3 -> 32-col slice
  const int quad = lane >> 4, l15 = lane & 15;

  const int r0 = tid >> 2, kc = tid & 3;     // r0: 0..63, kc: 0..3
  int ga = tm * 64 + r0;  if (ga > M - 1) ga = M - 1;
  const int gb0 = tn * 128 + r0;
  const int gb1 = tn * 128 + 64 + r0;
  const unsigned short* gA  = A + (size_t)ga * 512 + kc * 8;
  const unsigned short* gB0 = Bt + (size_t)gb0 * 512 + kc * 8;
  const unsigned short* gB1 = Bt + (size_t)gb1 * 512 + kc * 8;
  const int loff  = r0 * 32 + kc * 8;
  const int loff1 = (64 + r0) * 32 + kc * 8;
  const int ABUF = 64 * 32, BBUF = 128 * 32;

  f32x4 acc[4][2];
  #pragma unroll
  for (int i = 0; i < 4; i++)
    #pragma unroll
    for (int j = 0; j < 2; j++) {
      f32x4 z = {0.f, 0.f, 0.f, 0.f};
      acc[i][j] = z;
    }

  load_lds16(gA,  &As[loff]);
  load_lds16(gB0, &Bs[loff]);
  load_lds16(gB1, &Bs[loff1]);
  __syncthreads();

  for (int it = 0; it < 16; ++it) {
    const int ca = (it & 1) * ABUF, cb = (it & 1) * BBUF;
    if (it < 15) {
      const int k1 = (it + 1) * 32;
      const int na = ((it & 1) ^ 1) * ABUF, nb = ((it & 1) ^ 1) * BBUF;
      load_lds16(gA + k1,  &As[na + loff]);
      load_lds16(gB0 + k1, &Bs[nb + loff]);
      load_lds16(gB1 + k1, &Bs[nb + loff1]);
    }
    bf16x8 af[4], bfr[2];
    #pragma unroll
    for (int i = 0; i < 4; i++)
      af[i] = *(const bf16x8*)&As[ca + (i * 16 + l15) * 32 + quad * 8];
    #pragma unroll
    for (int j = 0; j < 2; j++)
      bfr[j] = *(const bf16x8*)&Bs[cb + (wn * 32 + j * 16 + l15) * 32 + quad * 8];
    #pragma unroll
    for (int i = 0; i < 4; i++)
      #pragma unroll
      for (int j = 0; j < 2; j++)
        acc[i][j] = mfma16(af[i], bfr[j], acc[i][j]);
    __syncthreads();
  }

  // C/D layout col=lane&15, row=quad*4+reg  [m89-verified]
  #pragma unroll
  for (int i = 0; i < 4; i++) {
    #pragma unroll
    for (int r = 0; r < 4; r++) {
      const int row = tm * 64 + i * 16 + quad * 4 + r;
      if (row < M) {
        float dv = 1.f;
        if (SCALED) {
          int c = cntp[row]; if (c > ELLCAP) c = ELLCAP;
          dv = rsqrtf((float)(1 + c));
        }
        #pragma unroll
        for (int j = 0; j < 2; j++) {
          const int col = tn * 128 + wn * 32 + j * 16 + l15;
          if (col < Ncols)
            C[(size_t)row * ldc + col] = f2b(acc[i][j][r] * dv);
        }
      }
    }
  }
}

// ===== 64x128 GEMM tile, fp32 A (cvt in staging), bf16 out, dinv-prescaled; ldc=512 =====
__device__ void gemm64_f32A(const float* __restrict__ A, const unsigned short* __restrict__ Bt,
                            unsigned short* __restrict__ C, const int* __restrict__ cntp,
                            int M, int tm, int tn,
                            unsigned short* __restrict__ As, unsigned short* __restrict__ Bs)
{
  const int tid = threadIdx.x;
  const int lane = tid & 63;
  const int wn = tid >> 6;
  const int quad = lane >> 4, l15 = lane & 15;

  const int r0 = tid >> 2, kc = tid & 3;
  int ga = tm * 64 + r0;  if (ga > M - 1) ga = M - 1;
  const int gb0 = tn * 128 + r0;
  const int gb1 = tn * 128 + 64 + r0;
  const float* gA = A + (size_t)ga * 512 + kc * 8;
  const unsigned short* gB0 = Bt + (size_t)gb0 * 512 + kc * 8;
  const unsigned short* gB1 = Bt + (size_t)gb1 * 512 + kc * 8;
  const int loff  = r0 * 32 + kc * 8;
  const int loff1 = (64 + r0) * 32 + kc * 8;
  const int ABUF = 64 * 32, BBUF = 128 * 32;

  f32x4 acc[4][2];
  #pragma unroll
  for (int i = 0; i < 4; i++)
    #pragma unroll
    for (int j = 0; j < 2; j++) {
      f32x4 z = {0.f, 0.f, 0.f, 0.f};
      acc[i][j] = z;
    }

  {
    float4 a0 = *(const float4*)(gA), a1 = *(const float4*)(gA + 4);
    *(uint4*)&As[loff] = cvt8(a0, a1);
    load_lds16(gB0, &Bs[loff]);
    load_lds16(gB1, &Bs[loff1]);
  }
  __syncthreads();

  for (int it = 0; it < 16; ++it) {
    const int ca = (it & 1) * ABUF, cb = (it & 1) * BBUF;
    const int na = ((it & 1) ^ 1) * ABUF, nb = ((it & 1) ^ 1) * BBUF;
    float4 a0, a1;
    if (it < 15) {
      const int k1 = (it + 1) * 32;
      a0 = *(const float4*)(gA + k1);  a1 = *(const float4*)(gA + k1 + 4);
      load_lds16(gB0 + k1, &Bs[nb + loff]);
      load_lds16(gB1 + k1, &Bs[nb + loff1]);
    }
    bf16x8 af[4], bfr[2];
    #pragma unroll
    for (int i = 0; i < 4; i++)
      af[i] = *(const bf16x8*)&As[ca + (i * 16 + l15) * 32 + quad * 8];
    #pragma unroll
    for (int j = 0; j < 2; j++)
      bfr[j] = *(const bf16x8*)&Bs[cb + (wn * 32 + j * 16 + l15) * 32 + quad * 8];
    #pragma unroll
    for (int i = 0; i < 4; i++)
      #pragma unroll
      for (int j = 0; j < 2; j++)
        acc[i][j] = mfma16(af[i], bfr[j], acc[i][j]);
    if (it < 15) *(uint4*)&As[na + loff] = cvt8(a0, a1);
    __syncthreads();
  }

  #pragma unroll
  for (int i = 0; i < 4; i++) {
    #pragma unroll
    for (int r = 0; r < 4; r++) {
      const int row = tm * 64 + i * 16 + quad * 4 + r;
      if (row < M) {
        int c = cntp[row]; if (c > ELLCAP) c = ELLCAP;
        const float dv = rsqrtf((float)(1 + c));
        #pragma unroll
        for (int j = 0; j < 2; j++) {
          const int col = tn * 128 + wn * 32 + j * 16 + l15;
          C[(size_t)row * 512 + col] = f2b(acc[i][j][r] * dv);
        }
      }
    }
  }
}

// ---- LDS-tiled 64x64 transpose: W fp32 [512][ncols] -> Wt bf16 [.][512] ----
__device__ void wtrans_tile(const float* __restrict__ W, unsigned short* __restrict__ Wt,
                            int ncols, int tr0, int tc0)
{
  __shared__ float tile[64][65];
  const int t = threadIdx.x;
  const int r = t >> 2, c4 = t & 3;
  #pragma unroll
  for (int i = 0; i < 4; i++) {
    int col = c4 * 16 + i * 4;
    int gc = tc0 + col;
    float4 v;
    if (gc + 3 < ncols) {
      v = *(const float4*)&W[(size_t)(tr0 + r) * ncols + gc];
    } else {
      v.x = (gc + 0 < ncols) ? W[(size_t)(tr0 + r) * ncols + gc + 0] : 0.f;
      v.y = (gc + 1 < ncols) ? W[(size_t)(tr0 + r) * ncols + gc + 1] : 0.f;
      v.z = (gc + 2 < ncols) ? W[(size_t)(tr0 + r) * ncols + gc + 2] : 0.f;
      v.w = (gc + 3 < ncols) ? W[(size_t)(tr0 + r) * ncols + gc + 3] : 0.f;
    }
    tile[r][col] = v.x; tile[r][col + 1] = v.y;
    tile[r][col + 2] = v.z; tile[r][col + 3] = v.w;
  }
  __syncthreads();
  const int o = t >> 2;
  #pragma unroll
  for (int i = 0; i < 4; i++) {
    int k = c4 * 16 + i * 4;
    ushort4 u;
    u.x = f2b(tile[k + 0][o]); u.y = f2b(tile[k + 1][o]);
    u.z = f2b(tile[k + 2][o]); u.w = f2b(tile[k + 3][o]);
    *(ushort4*)&Wt[(size_t)(tc0 + o) * 512 + tr0 + k] = u;
  }
}

// ================= kernel A: prep_fill (grid 240) =================
__global__ __launch_bounds__(256)
void prep_fill(const float* __restrict__ W1, const float* __restrict__ Wc,
               const float* __restrict__ W2, const int* __restrict__ src,
               const int* __restrict__ dst, int* __restrict__ cnt,
               int* __restrict__ ell, unsigned short* __restrict__ W1t,
               unsigned short* __restrict__ Wct, unsigned short* __restrict__ w2b, int E)
{
  if (blockIdx.x < 64) { wtrans_tile(W1, W1t, 512, (blockIdx.x >> 3) * 64, (blockIdx.x & 7) * 64); return; }
  if (blockIdx.x < 80) { int b = blockIdx.x - 64; wtrans_tile(Wc, Wct, 100, (b >> 1) * 64, (b & 1) * 64); return; }
  const int t0 = (blockIdx.x - 80) * 256 + threadIdx.x;
  const int FT = 160 * 256;
  const float4* W24 = (const float4*)W2;
  uint4* w2b4 = (uint4*)w2b;
  for (int i = t0; i < 512 * 512 / 8; i += FT)
    w2b4[i] = cvt8(W24[i * 2], W24[i * 2 + 1]);
  for (int e = t0; e < E; e += FT) {
    int s = src[e], d = dst[e];
    int pos = atomicAdd(&cnt[d], 1);
    if (pos < ELLCAP) ell[d * ELLCAP + pos] = s;   // P(overflow) ~ 1e-18 @ Poisson(16)
  }
}

// ===== kernel B: gemm1 (628 tiles, XCD-chunked for A-tile L2 reuse) + fold + bias =====
__global__ __launch_bounds__(256)
void gemm1_fold(const float* __restrict__ x, const unsigned short* __restrict__ W1t,
                unsigned short* __restrict__ B2, const int* __restrict__ cnt,
                const unsigned short* __restrict__ Wct, const unsigned short* __restrict__ w2b,
                unsigned short* __restrict__ W2WcT,
                const float* __restrict__ b2, const float* __restrict__ Wc,
                const float* __restrict__ bc, float* __restrict__ bias2c)
{
  __shared__ __align__(16) unsigned short As[2 * 64 * 32];
  __shared__ __align__(16) unsigned short Bs[2 * 128 * 32];
  const int b = blockIdx.x;
  if (b < 628) {
    // bijective XCD-chunk swizzle [m204]: XCD k (= b%8, round-robin dispatch) gets a
    // contiguous chunk of tile space t (tn-minor), so the 4 tn-tiles sharing one
    // 128KB fp32 A-tile run on the SAME XCD -> A hits L2 instead of 4x HBM refetch.
    // 628 = 8*78 + 4: XCDs 0..3 get 79 tiles, XCDs 4..7 get 78.
    const int xcd = b & 7, loc = b >> 3;
    const int base = (xcd < 4) ? xcd * 79 : 316 + (xcd - 4) * 78;
    const int t = base + loc;
    gemm64_f32A(x, W1t, B2, cnt, NN, t >> 2, t & 3, As, Bs);
  } else if (b < 636) {               // fold: M=128 -> 2 tm x 4 tn
    const int g = b - 628;
    gemm64<false>(Wct, w2b, W2WcT, nullptr, 128, 512, 512, g >> 2, g & 3, As, Bs);
  } else {
    const int j = threadIdx.x;
    if (j < 128) {
      float s = 0.f;
      if (j < 100) {
        s = bc[j];
        for (int k = 0; k < 512; k++) s = fmaf(b2[k], Wc[k * 100 + j], s);
      }
      bias2c[j] = s;
    }
  }
}

// ================= kernel 3: gather1 (ELL, prescaled rows -> pure row-sum) =================
__device__ __forceinline__ void add8(float* a, uint4 v) {
  a[0] += b2f((unsigned short)(v.x & 0xffffu));
  a[1] += b2f((unsigned short)(v.x >> 16));
  a[2] += b2f((unsigned short)(v.y & 0xffffu));
  a[3] += b2f((unsigned short)(v.y >> 16));
  a[4] += b2f((unsigned short)(v.z & 0xffffu));
  a[5] += b2f((unsigned short)(v.z >> 16));
  a[6] += b2f((unsigned short)(v.w & 0xffffu));
  a[7] += b2f((unsigned short)(v.w >> 16));
}

__global__ __launch_bounds__(256)
void gather1(const unsigned short* __restrict__ h, const int* __restrict__ cnt,
             const int* __restrict__ ell, const float* __restrict__ bias,
             unsigned short* __restrict__ outb, int n)
{
  int node = blockIdx.x * 4 + (threadIdx.x >> 6);
  if (node >= n) return;
  const int lane = threadIdx.x & 63;
  const int c8 = lane * 8;

  int cd = cnt[node]; if (cd > ELLCAP) cd = ELLCAP;
  const float dinv = rsqrtf((float)(1 + cd));
  uint4 hv = *(const uint4*)&h[(size_t)node * 512 + c8];
  float a[8] = {0.f, 0.f, 0.f, 0.f, 0.f, 0.f, 0.f, 0.f};
  add8(a, hv);                     // self term B2'[d]

  const int* row = ell + node * ELLCAP;
  int j = 0;
  for (; j + 8 <= cd; j += 8) {
    int ss[8]; uint4 vv[8];
    #pragma unroll
    for (int q = 0; q < 8; q++) ss[q] = row[j + q];
    #pragma unroll
    for (int q = 0; q < 8; q++) vv[q] = *(const uint4*)&h[(size_t)ss[q] * 512 + c8];
    #pragma unroll
    for (int q = 0; q < 8; q++) add8(a, vv[q]);
  }
  for (; j < cd; ++j) {
    int s = row[j];
    uint4 v = *(const uint4*)&h[(size_t)s * 512 + c8];
    add8(a, v);
  }

  const float4* bp = (const float4*)&bias[c8];
  float4 b0 = bp[0], b1 = bp[1];
  float bb[8] = {b0.x, b0.y, b0.z, b0.w, b1.x, b1.y, b1.z, b1.w};
  #pragma unroll
  for (int q = 0; q < 8; q++) a[q] = fmaxf(fmaf(a[q], dinv, bb[q]), 0.f);
  uint4 o;
  o.x = (unsigned int)f2b(a[0]) | ((unsigned int)f2b(a[1]) << 16);
  o.y = (unsigned int)f2b(a[2]) | ((unsigned int)f2b(a[3]) << 16);
  o.z = (unsigned int)f2b(a[4]) | ((unsigned int)f2b(a[5]) << 16);
  o.w = (unsigned int)f2b(a[6]) | ((unsigned int)f2b(a[7]) << 16);
  *(uint4*)&outb[(size_t)node * 512 + c8] = o;
}

// ===== kernel 4: gemm2c: Z' = dinv * (B1 @ W2WcT^T) (bf16, 128 cols); 157 tiles =====
__global__ __launch_bounds__(256)
void gemm2c(const unsigned short* __restrict__ B1, const unsigned short* __restrict__ W2WcT,
            unsigned short* __restrict__ Z, const int* __restrict__ cnt)
{
  __shared__ __align__(16) unsigned short As[2 * 64 * 32];
  __shared__ __align__(16) unsigned short Bs[2 * 128 * 32];
  gemm64<true>(B1, W2WcT, Z, cnt, NN, 128, 128, blockIdx.x, 0, As, Bs);
}

// ================= kernel 5: gather2c (ELL, prescaled rows -> pure row-sum) =================
__global__ __launch_bounds__(256)
void gather2c(const unsigned short* __restrict__ Z, const int* __restrict__ cnt,
              const int* __restrict__ ell, const float* __restrict__ bias2c,
              float* __restrict__ out, int n)
{
  int node = blockIdx.x * 4 + (threadIdx.x >> 6);
  if (node >= n) return;
  const int lane = threadIdx.x & 63;
  const int c2 = lane * 2;

  int cd = cnt[node]; if (cd > ELLCAP) cd = ELLCAP;
  const float dinv = rsqrtf((float)(1 + cd));
  unsigned int hv = *(const unsigned int*)&Z[(size_t)node * 128 + c2];
  float a0 = b2f((unsigned short)(hv & 0xffffu));
  float a1 = b2f((unsigned short)(hv >> 16));

  const int* row = ell + node * ELLCAP;
  int j = 0;
  for (; j + 8 <= cd; j += 8) {
    int ss[8]; unsigned int vv[8];
    #pragma unroll
    for (int q = 0; q < 8; q++) ss[q] = row[j + q];
    #pragma unroll
    for (int q = 0; q < 8; q++) vv[q] = *(const unsigned int*)&Z[(size_t)ss[q] * 128 + c2];
    #pragma unroll
    for (int q = 0; q < 8; q++) {
      a0 += b2f((unsigned short)(vv[q] & 0xffffu));
      a1 += b2f((unsigned short)(vv[q] >> 16));
    }
  }
  for (; j < cd; ++j) {
    int s = row[j];
    unsigned int v = *(const unsigned int*)&Z[(size_t)s * 128 + c2];
    a0 += b2f((unsigned short)(v & 0xffffu));
    a1 += b2f((unsigned short)(v >> 16));
  }
  if (c2 < 100) {
    const float2 bb = *(const float2*)&bias2c[c2];
    *(float2*)&out[(size_t)node * 100 + c2] =
        make_float2(fmaf(a0, dinv, bb.x), fmaf(a1, dinv, bb.y));
  }
}

extern "C" void kernel_launch(void* const* d_in, const int* in_sizes, int n_in,
                              void* d_out, int out_size, void* d_ws, size_t ws_size,
                              hipStream_t stream) {
  const float* x  = (const float*)d_in[0];
  const int*   ei = (const int*)d_in[1];
  const float* W1 = (const float*)d_in[2];
  const float* b1 = (const float*)d_in[3];
  const float* W2 = (const float*)d_in[4];
  const float* b2 = (const float*)d_in[5];
  const float* Wc = (const float*)d_in[6];
  const float* bc = (const float*)d_in[7];
  float* out = (float*)d_out;

  const int n = NN;
  const int E = in_sizes[1] / 2;
  const int* src = ei;
  const int* dst = ei + E;

  // workspace (~26 MB)
  char* w = (char*)d_ws;
  int* cnt = (int*)w;                       w += ((n * 4 + 255) / 256) * 256;
  int* ell = (int*)w;                       w += ((n * ELLCAP * 4 + 255) / 256) * 256;
  float* bias2c = (float*)w;                w += 512;
  unsigned short* W1t = (unsigned short*)w; w += 512 * 512 * 2;
  unsigned short* Wct = (unsigned short*)w; w += 128 * 512 * 2;
  unsigned short* w2b = (unsigned short*)w; w += 512 * 512 * 2;
  unsigned short* W2WcT = (unsigned short*)w; w += 128 * 512 * 2;
  unsigned short* B1  = (unsigned short*)w; w += (size_t)n * 512 * 2;
  unsigned short* B2  = (unsigned short*)w; w += (size_t)n * 512 * 2;
  unsigned short* Z   = (unsigned short*)w; w += (size_t)n * 128 * 2;

  const int nb_g = (n + 3) / 4;

  hipMemsetAsync(cnt, 0, n * sizeof(int), stream);
  prep_fill<<<240, 256, 0, stream>>>(W1, Wc, W2, src, dst, cnt, ell, W1t, Wct, w2b, E);
  gemm1_fold<<<637, 256, 0, stream>>>(x, W1t, B2, cnt, Wct, w2b, W2WcT, b2, Wc, bc, bias2c);
  gather1<<<nb_g, 256, 0, stream>>>(B2, cnt, ell, b1, B1, n);
  gemm2c<<<157, 256, 0, stream>>>(B1, W2WcT, Z, cnt);
  gather2c<<<nb_g, 256, 0, stream>>>(Z, cnt, ell, bias2c, out, n);
}

// Round 7
// 151.543 us; speedup vs baseline: 4.0437x; 1.0351x over previous
//
#include <hip/hip_runtime.h>
#include <hip/hip_bf16.h>
#include <stdint.h>

typedef __bf16 bf16_t;
typedef bf16_t bf16x8 __attribute__((ext_vector_type(8)));
typedef float f32x4 __attribute__((ext_vector_type(4)));

#define NN 10000
#define ELLCAP 64

__device__ __forceinline__ float b2f(unsigned short u) {
  union { unsigned int i; float f; } c; c.i = ((unsigned int)u) << 16; return c.f;
}
__device__ __forceinline__ unsigned short f2b(float f) {
  union { float f; unsigned int i; } c; c.f = f;
  unsigned int x = c.i;
  x += 0x7FFFu + ((x >> 16) & 1u);
  return (unsigned short)(x >> 16);
}
__device__ __forceinline__ uint4 cvt8(float4 a, float4 b) {
  uint4 r;
  r.x = (unsigned int)f2b(a.x) | ((unsigned int)f2b(a.y) << 16);
  r.y = (unsigned int)f2b(a.z) | ((unsigned int)f2b(a.w) << 16);
  r.z = (unsigned int)f2b(b.x) | ((unsigned int)f2b(b.y) << 16);
  r.w = (unsigned int)f2b(b.z) | ((unsigned int)f2b(b.w) << 16);
  return r;
}
__device__ __forceinline__ void load_lds16(const void* g, void* l) {
  __builtin_amdgcn_global_load_lds(
      (const __attribute__((address_space(1))) unsigned int*)g,
      (__attribute__((address_space(3))) unsigned int*)l, 16, 0, 0);
}
__device__ __forceinline__ f32x4 mfma16(bf16x8 a, bf16x8 b, f32x4 c) {
  return __builtin_amdgcn_mfma_f32_16x16x32_bf16(a, b, c, 0, 0, 0);
}

// ===== 64x128 GEMM tile, bf16 A via global_load_lds. 4 waves: wn = wave id =====
// SCALED: multiply output row r by rsqrt(1+min(cnt[r],ELLCAP)) (symmetric-norm prescale).
template <bool SCALED>
__device__ void gemm64(const unsigned short* __restrict__ A, const unsigned short* __restrict__ Bt,
                       unsigned short* __restrict__ C, const int* __restrict__ cntp,
                       int M, int Ncols, int ldc, int tm, int tn,
                       unsigned short* __restrict__ As, unsigned short* __restrict__ Bs)
{
  const int tid = threadIdx.x;
  const int lane = tid & 63;
  const int wn = tid >> 6;           // 0..3 -> 32-col slice
  const int quad = lane >> 4, l15 = lane & 15;

  const int r0 = tid >> 2, kc = tid & 3;     // r0: 0..63, kc: 0..3
  int ga = tm * 64 + r0;  if (ga > M - 1) ga = M - 1;
  const int gb0 = tn * 128 + r0;
  const int gb1 = tn * 128 + 64 + r0;
  const unsigned short* gA  = A + (size_t)ga * 512 + kc * 8;
  const unsigned short* gB0 = Bt + (size_t)gb0 * 512 + kc * 8;
  const unsigned short* gB1 = Bt + (size_t)gb1 * 512 + kc * 8;
  const int loff  = r0 * 32 + kc * 8;
  const int loff1 = (64 + r0) * 32 + kc * 8;
  const int ABUF = 64 * 32, BBUF = 128 * 32;

  f32x4 acc[4][2];
  #pragma unroll
  for (int i = 0; i < 4; i++)
    #pragma unroll
    for (int j = 0; j < 2; j++) {
      f32x4 z = {0.f, 0.f, 0.f, 0.f};
      acc[i][j] = z;
    }

  load_lds16(gA,  &As[loff]);
  load_lds16(gB0, &Bs[loff]);
  load_lds16(gB1, &Bs[loff1]);
  __syncthreads();

  for (int it = 0; it < 16; ++it) {
    const int ca = (it & 1) * ABUF, cb = (it & 1) * BBUF;
    if (it < 15) {
      const int k1 = (it + 1) * 32;
      const int na = ((it & 1) ^ 1) * ABUF, nb = ((it & 1) ^ 1) * BBUF;
      load_lds16(gA + k1,  &As[na + loff]);
      load_lds16(gB0 + k1, &Bs[nb + loff]);
      load_lds16(gB1 + k1, &Bs[nb + loff1]);
    }
    bf16x8 af[4], bfr[2];
    #pragma unroll
    for (int i = 0; i < 4; i++)
      af[i] = *(const bf16x8*)&As[ca + (i * 16 + l15) * 32 + quad * 8];
    #pragma unroll
    for (int j = 0; j < 2; j++)
      bfr[j] = *(const bf16x8*)&Bs[cb + (wn * 32 + j * 16 + l15) * 32 + quad * 8];
    #pragma unroll
    for (int i = 0; i < 4; i++)
      #pragma unroll
      for (int j = 0; j < 2; j++)
        acc[i][j] = mfma16(af[i], bfr[j], acc[i][j]);
    __syncthreads();
  }

  // C/D layout col=lane&15, row=quad*4+reg  [m89-verified]
  #pragma unroll
  for (int i = 0; i < 4; i++) {
    #pragma unroll
    for (int r = 0; r < 4; r++) {
      const int row = tm * 64 + i * 16 + quad * 4 + r;
      if (row < M) {
        float dv = 1.f;
        if (SCALED) {
          int c = cntp[row]; if (c > ELLCAP) c = ELLCAP;
          dv = rsqrtf((float)(1 + c));
        }
        #pragma unroll
        for (int j = 0; j < 2; j++) {
          const int col = tn * 128 + wn * 32 + j * 16 + l15;
          if (col < Ncols)
            C[(size_t)row * ldc + col] = f2b(acc[i][j][r] * dv);
        }
      }
    }
  }
}

// ===== 64x128 GEMM tile, fp32 A (cvt in staging), bf16 out (unscaled); ldc=512 =====
__device__ void gemm64_f32A(const float* __restrict__ A, const unsigned short* __restrict__ Bt,
                            unsigned short* __restrict__ C, int M, int tm, int tn,
                            unsigned short* __restrict__ As, unsigned short* __restrict__ Bs)
{
  const int tid = threadIdx.x;
  const int lane = tid & 63;
  const int wn = tid >> 6;
  const int quad = lane >> 4, l15 = lane & 15;

  const int r0 = tid >> 2, kc = tid & 3;
  int ga = tm * 64 + r0;  if (ga > M - 1) ga = M - 1;
  const int gb0 = tn * 128 + r0;
  const int gb1 = tn * 128 + 64 + r0;
  const float* gA = A + (size_t)ga * 512 + kc * 8;
  const unsigned short* gB0 = Bt + (size_t)gb0 * 512 + kc * 8;
  const unsigned short* gB1 = Bt + (size_t)gb1 * 512 + kc * 8;
  const int loff  = r0 * 32 + kc * 8;
  const int loff1 = (64 + r0) * 32 + kc * 8;
  const int ABUF = 64 * 32, BBUF = 128 * 32;

  f32x4 acc[4][2];
  #pragma unroll
  for (int i = 0; i < 4; i++)
    #pragma unroll
    for (int j = 0; j < 2; j++) {
      f32x4 z = {0.f, 0.f, 0.f, 0.f};
      acc[i][j] = z;
    }

  {
    float4 a0 = *(const float4*)(gA), a1 = *(const float4*)(gA + 4);
    *(uint4*)&As[loff] = cvt8(a0, a1);
    load_lds16(gB0, &Bs[loff]);
    load_lds16(gB1, &Bs[loff1]);
  }
  __syncthreads();

  for (int it = 0; it < 16; ++it) {
    const int ca = (it & 1) * ABUF, cb = (it & 1) * BBUF;
    const int na = ((it & 1) ^ 1) * ABUF, nb = ((it & 1) ^ 1) * BBUF;
    float4 a0, a1;
    if (it < 15) {
      const int k1 = (it + 1) * 32;
      a0 = *(const float4*)(gA + k1);  a1 = *(const float4*)(gA + k1 + 4);
      load_lds16(gB0 + k1, &Bs[nb + loff]);
      load_lds16(gB1 + k1, &Bs[nb + loff1]);
    }
    bf16x8 af[4], bfr[2];
    #pragma unroll
    for (int i = 0; i < 4; i++)
      af[i] = *(const bf16x8*)&As[ca + (i * 16 + l15) * 32 + quad * 8];
    #pragma unroll
    for (int j = 0; j < 2; j++)
      bfr[j] = *(const bf16x8*)&Bs[cb + (wn * 32 + j * 16 + l15) * 32 + quad * 8];
    #pragma unroll
    for (int i = 0; i < 4; i++)
      #pragma unroll
      for (int j = 0; j < 2; j++)
        acc[i][j] = mfma16(af[i], bfr[j], acc[i][j]);
    if (it < 15) *(uint4*)&As[na + loff] = cvt8(a0, a1);
    __syncthreads();
  }

  #pragma unroll
  for (int i = 0; i < 4; i++) {
    #pragma unroll
    for (int r = 0; r < 4; r++) {
      const int row = tm * 64 + i * 16 + quad * 4 + r;
      if (row < M) {
        #pragma unroll
        for (int j = 0; j < 2; j++) {
          const int col = tn * 128 + wn * 32 + j * 16 + l15;
          C[(size_t)row * 512 + col] = f2b(acc[i][j][r]);
        }
      }
    }
  }
}

// ---- LDS-tiled 64x64 transpose: W fp32 [512][ncols] -> Wt bf16 [.][512] ----
__device__ void wtrans_tile(const float* __restrict__ W, unsigned short* __restrict__ Wt,
                            int ncols, int tr0, int tc0)
{
  __shared__ float tile[64][65];
  const int t = threadIdx.x;
  const int r = t >> 2, c4 = t & 3;
  #pragma unroll
  for (int i = 0; i < 4; i++) {
    int col = c4 * 16 + i * 4;
    int gc = tc0 + col;
    float4 v;
    if (gc + 3 < ncols) {
      v = *(const float4*)&W[(size_t)(tr0 + r) * ncols + gc];
    } else {
      v.x = (gc + 0 < ncols) ? W[(size_t)(tr0 + r) * ncols + gc + 0] : 0.f;
      v.y = (gc + 1 < ncols) ? W[(size_t)(tr0 + r) * ncols + gc + 1] : 0.f;
      v.z = (gc + 2 < ncols) ? W[(size_t)(tr0 + r) * ncols + gc + 2] : 0.f;
      v.w = (gc + 3 < ncols) ? W[(size_t)(tr0 + r) * ncols + gc + 3] : 0.f;
    }
    tile[r][col] = v.x; tile[r][col + 1] = v.y;
    tile[r][col + 2] = v.z; tile[r][col + 3] = v.w;
  }
  __syncthreads();
  const int o = t >> 2;
  #pragma unroll
  for (int i = 0; i < 4; i++) {
    int k = c4 * 16 + i * 4;
    ushort4 u;
    u.x = f2b(tile[k + 0][o]); u.y = f2b(tile[k + 1][o]);
    u.z = f2b(tile[k + 2][o]); u.w = f2b(tile[k + 3][o]);
    *(ushort4*)&Wt[(size_t)(tc0 + o) * 512 + tr0 + k] = u;
  }
}

// ========== K1: prep1 (grid 240) — transposes + W2 cvt + cnt zero ==========
// No atomics here; the ELL build moves into K2 where it overlaps gemm1.
__global__ __launch_bounds__(256)
void prep1(const float* __restrict__ W1, const float* __restrict__ Wc,
           const float* __restrict__ W2, int* __restrict__ cnt,
           unsigned short* __restrict__ W1t, unsigned short* __restrict__ Wct,
           unsigned short* __restrict__ w2b)
{
  if (blockIdx.x < 64) { wtrans_tile(W1, W1t, 512, (blockIdx.x >> 3) * 64, (blockIdx.x & 7) * 64); return; }
  if (blockIdx.x < 80) { int b = blockIdx.x - 64; wtrans_tile(Wc, Wct, 100, (b >> 1) * 64, (b & 1) * 64); return; }
  const int t0 = (blockIdx.x - 80) * 256 + threadIdx.x;
  const int FT = 160 * 256;   // 40960 threads
  const float4* W24 = (const float4*)W2;
  uint4* w2b4 = (uint4*)w2b;
  for (int i = t0; i < 512 * 512 / 8; i += FT)
    w2b4[i] = cvt8(W24[i * 2], W24[i * 2 + 1]);
  if (t0 < NN) cnt[t0] = 0;   // replaces the memset dispatch (NN < FT)
}

// ===== K2: gemm1 (628 tiles, XCD-chunked) + W2Wc fold (8) + bias (1) + ELL build (163) =====
// ELL build (blocks 637..799) overlaps the GEMM — disjoint data, no ordering needed.
// gemm1 output is UNSCALED; norms are applied per-edge in gather1 (R0-form, measured equal).
__global__ __launch_bounds__(256)
void gemm1_fold_ell(const float* __restrict__ x, const unsigned short* __restrict__ W1t,
                    unsigned short* __restrict__ B2,
                    const unsigned short* __restrict__ Wct, const unsigned short* __restrict__ w2b,
                    unsigned short* __restrict__ W2WcT,
                    const float* __restrict__ b2, const float* __restrict__ Wc,
                    const float* __restrict__ bc, float* __restrict__ bias2c,
                    const int* __restrict__ src, const int* __restrict__ dst,
                    int* __restrict__ cnt, int* __restrict__ ell, int E)
{
  __shared__ __align__(16) unsigned short As[2 * 64 * 32];
  __shared__ __align__(16) unsigned short Bs[2 * 128 * 32];
  const int b = blockIdx.x;
  if (b < 628) {
    // bijective XCD-chunk swizzle [m204]: the 4 tn-tiles sharing one 128KB fp32
    // A-tile run on the SAME XCD -> A hits L2 instead of 4x HBM refetch.
    const int xcd = b & 7, loc = b >> 3;
    const int base = (xcd < 4) ? xcd * 79 : 316 + (xcd - 4) * 78;
    const int t = base + loc;
    gemm64_f32A(x, W1t, B2, NN, t >> 2, t & 3, As, Bs);
  } else if (b < 636) {               // fold: M=128 -> 2 tm x 4 tn
    const int g = b - 628;
    gemm64<false>(Wct, w2b, W2WcT, nullptr, 128, 512, 512, g >> 2, g & 3, As, Bs);
  } else if (b == 636) {
    const int j = threadIdx.x;
    if (j < 128) {
      float s = 0.f;
      if (j < 100) {
        s = bc[j];
        for (int k = 0; k < 512; k++) s = fmaf(b2[k], Wc[k * 100 + j], s);
      }
      bias2c[j] = s;
    }
  } else {                            // ELL build: 163 blocks stream E edges
    const int t0 = (b - 637) * 256 + threadIdx.x;
    const int FT = 163 * 256;
    for (int e = t0; e < E; e += FT) {
      int s = src[e], d = dst[e];
      int pos = atomicAdd(&cnt[d], 1);
      if (pos < ELLCAP) ell[d * ELLCAP + pos] = s;   // P(overflow) ~ 1e-18 @ Poisson(16)
    }
  }
}

// ========= K3: gather1 (R0-form: per-edge symmetric norms, 16B/lane) =========
__device__ __forceinline__ void acc8(float* a, uint4 v, float nm) {
  a[0] = fmaf(b2f((unsigned short)(v.x & 0xffffu)), nm, a[0]);
  a[1] = fmaf(b2f((unsigned short)(v.x >> 16)),     nm, a[1]);
  a[2] = fmaf(b2f((unsigned short)(v.y & 0xffffu)), nm, a[2]);
  a[3] = fmaf(b2f((unsigned short)(v.y >> 16)),     nm, a[3]);
  a[4] = fmaf(b2f((unsigned short)(v.z & 0xffffu)), nm, a[4]);
  a[5] = fmaf(b2f((unsigned short)(v.z >> 16)),     nm, a[5]);
  a[6] = fmaf(b2f((unsigned short)(v.w & 0xffffu)), nm, a[6]);
  a[7] = fmaf(b2f((unsigned short)(v.w >> 16)),     nm, a[7]);
}

__global__ __launch_bounds__(256)
void gather1(const unsigned short* __restrict__ h, const int* __restrict__ cnt,
             const int* __restrict__ ell, const float* __restrict__ bias,
             unsigned short* __restrict__ outb, int n)
{
  int node = blockIdx.x * 4 + (threadIdx.x >> 6);
  if (node >= n) return;
  const int lane = threadIdx.x & 63;
  const int c8 = lane * 8;

  int cd = cnt[node]; if (cd > ELLCAP) cd = ELLCAP;
  const float fd = (float)(1 + cd);
  const float slf = 1.0f / fd;
  uint4 hv = *(const uint4*)&h[(size_t)node * 512 + c8];
  const float4* bp = (const float4*)&bias[c8];
  float4 b0 = bp[0], b1 = bp[1];
  float a[8] = {b0.x, b0.y, b0.z, b0.w, b1.x, b1.y, b1.z, b1.w};
  acc8(a, hv, slf);

  const int* row = ell + node * ELLCAP;
  int j = 0;
  for (; j + 8 <= cd; j += 8) {
    int ss[8]; uint4 vv[8]; float nm[8];
    #pragma unroll
    for (int q = 0; q < 8; q++) ss[q] = row[j + q];
    #pragma unroll
    for (int q = 0; q < 8; q++) vv[q] = *(const uint4*)&h[(size_t)ss[q] * 512 + c8];
    #pragma unroll
    for (int q = 0; q < 8; q++) nm[q] = rsqrtf((float)(1 + cnt[ss[q]]) * fd);
    #pragma unroll
    for (int q = 0; q < 8; q++) acc8(a, vv[q], nm[q]);
  }
  for (; j < cd; ++j) {
    int s = row[j];
    uint4 v = *(const uint4*)&h[(size_t)s * 512 + c8];
    acc8(a, v, rsqrtf((float)(1 + cnt[s]) * fd));
  }
  #pragma unroll
  for (int q = 0; q < 8; q++) a[q] = fmaxf(a[q], 0.f);
  uint4 o;
  o.x = (unsigned int)f2b(a[0]) | ((unsigned int)f2b(a[1]) << 16);
  o.y = (unsigned int)f2b(a[2]) | ((unsigned int)f2b(a[3]) << 16);
  o.z = (unsigned int)f2b(a[4]) | ((unsigned int)f2b(a[5]) << 16);
  o.w = (unsigned int)f2b(a[6]) | ((unsigned int)f2b(a[7]) << 16);
  *(uint4*)&outb[(size_t)node * 512 + c8] = o;
}

// ===== K4: gemm2c: Z' = dinv * (B1 @ W2WcT^T) (bf16, 128 cols); 157 tiles =====
__global__ __launch_bounds__(256)
void gemm2c(const unsigned short* __restrict__ B1, const unsigned short* __restrict__ W2WcT,
            unsigned short* __restrict__ Z, const int* __restrict__ cnt)
{
  __shared__ __align__(16) unsigned short As[2 * 64 * 32];
  __shared__ __align__(16) unsigned short Bs[2 * 128 * 32];
  gemm64<true>(B1, W2WcT, Z, cnt, NN, 128, 128, blockIdx.x, 0, As, Bs);
}

// ========= K5: gather2c (prescaled Z rows -> pure row-sum) =========
__global__ __launch_bounds__(256)
void gather2c(const unsigned short* __restrict__ Z, const int* __restrict__ cnt,
              const int* __restrict__ ell, const float* __restrict__ bias2c,
              float* __restrict__ out, int n)
{
  int node = blockIdx.x * 4 + (threadIdx.x >> 6);
  if (node >= n) return;
  const int lane = threadIdx.x & 63;
  const int c2 = lane * 2;

  int cd = cnt[node]; if (cd > ELLCAP) cd = ELLCAP;
  const float dinv = rsqrtf((float)(1 + cd));
  unsigned int hv = *(const unsigned int*)&Z[(size_t)node * 128 + c2];
  float a0 = b2f((unsigned short)(hv & 0xffffu));
  float a1 = b2f((unsigned short)(hv >> 16));

  const int* row = ell + node * ELLCAP;
  int j = 0;
  for (; j + 8 <= cd; j += 8) {
    int ss[8]; unsigned int vv[8];
    #pragma unroll
    for (int q = 0; q < 8; q++) ss[q] = row[j + q];
    #pragma unroll
    for (int q = 0; q < 8; q++) vv[q] = *(const unsigned int*)&Z[(size_t)ss[q] * 128 + c2];
    #pragma unroll
    for (int q = 0; q < 8; q++) {
      a0 += b2f((unsigned short)(vv[q] & 0xffffu));
      a1 += b2f((unsigned short)(vv[q] >> 16));
    }
  }
  for (; j < cd; ++j) {
    int s = row[j];
    unsigned int v = *(const unsigned int*)&Z[(size_t)s * 128 + c2];
    a0 += b2f((unsigned short)(v & 0xffffu));
    a1 += b2f((unsigned short)(v >> 16));
  }
  if (c2 < 100) {
    const float2 bb = *(const float2*)&bias2c[c2];
    *(float2*)&out[(size_t)node * 100 + c2] =
        make_float2(fmaf(a0, dinv, bb.x), fmaf(a1, dinv, bb.y));
  }
}

extern "C" void kernel_launch(void* const* d_in, const int* in_sizes, int n_in,
                              void* d_out, int out_size, void* d_ws, size_t ws_size,
                              hipStream_t stream) {
  const float* x  = (const float*)d_in[0];
  const int*   ei = (const int*)d_in[1];
  const float* W1 = (const float*)d_in[2];
  const float* b1 = (const float*)d_in[3];
  const float* W2 = (const float*)d_in[4];
  const float* b2 = (const float*)d_in[5];
  const float* Wc = (const float*)d_in[6];
  const float* bc = (const float*)d_in[7];
  float* out = (float*)d_out;

  const int n = NN;
  const int E = in_sizes[1] / 2;
  const int* src = ei;
  const int* dst = ei + E;

  // workspace (~26 MB)
  char* w = (char*)d_ws;
  int* cnt = (int*)w;                       w += ((n * 4 + 255) / 256) * 256;
  int* ell = (int*)w;                       w += ((n * ELLCAP * 4 + 255) / 256) * 256;
  float* bias2c = (float*)w;                w += 512;
  unsigned short* W1t = (unsigned short*)w; w += 512 * 512 * 2;
  unsigned short* Wct = (unsigned short*)w; w += 128 * 512 * 2;
  unsigned short* w2b = (unsigned short*)w; w += 512 * 512 * 2;
  unsigned short* W2WcT = (unsigned short*)w; w += 128 * 512 * 2;
  unsigned short* B1  = (unsigned short*)w; w += (size_t)n * 512 * 2;
  unsigned short* B2  = (unsigned short*)w; w += (size_t)n * 512 * 2;
  unsigned short* Z   = (unsigned short*)w; w += (size_t)n * 128 * 2;

  const int nb_g = (n + 3) / 4;

  prep1<<<240, 256, 0, stream>>>(W1, Wc, W2, cnt, W1t, Wct, w2b);
  gemm1_fold_ell<<<800, 256, 0, stream>>>(x, W1t, B2, Wct, w2b, W2WcT,
                                          b2, Wc, bc, bias2c, src, dst, cnt, ell, E);
  gather1<<<nb_g, 256, 0, stream>>>(B2, cnt, ell, b1, B1, n);
  gemm2c<<<157, 256, 0, stream>>>(B1, W2WcT, Z, cnt);
  gather2c<<<nb_g, 256, 0, stream>>>(Z, cnt, ell, bias2c, out, n);
}

// Round 8
// 148.830 us; speedup vs baseline: 4.1174x; 1.0182x over previous
//
#include <hip/hip_runtime.h>
#include <hip/hip_bf16.h>
#include <stdint.h>

typedef __bf16 bf16_t;
typedef bf16_t bf16x8 __attribute__((ext_vector_type(8)));
typedef float f32x4 __attribute__((ext_vector_type(4)));

#define NN 10000
#define ELLCAP 64

__device__ __forceinline__ float b2f(unsigned short u) {
  union { unsigned int i; float f; } c; c.i = ((unsigned int)u) << 16; return c.f;
}
__device__ __forceinline__ unsigned short f2b(float f) {
  union { float f; unsigned int i; } c; c.f = f;
  unsigned int x = c.i;
  x += 0x7FFFu + ((x >> 16) & 1u);
  return (unsigned short)(x >> 16);
}
__device__ __forceinline__ uint4 cvt8(float4 a, float4 b) {
  uint4 r;
  r.x = (unsigned int)f2b(a.x) | ((unsigned int)f2b(a.y) << 16);
  r.y = (unsigned int)f2b(a.z) | ((unsigned int)f2b(a.w) << 16);
  r.z = (unsigned int)f2b(b.x) | ((unsigned int)f2b(b.y) << 16);
  r.w = (unsigned int)f2b(b.z) | ((unsigned int)f2b(b.w) << 16);
  return r;
}
__device__ __forceinline__ void load_lds16(const void* g, void* l) {
  __builtin_amdgcn_global_load_lds(
      (const __attribute__((address_space(1))) unsigned int*)g,
      (__attribute__((address_space(3))) unsigned int*)l, 16, 0, 0);
}
__device__ __forceinline__ f32x4 mfma16(bf16x8 a, bf16x8 b, f32x4 c) {
  return __builtin_amdgcn_mfma_f32_16x16x32_bf16(a, b, c, 0, 0, 0);
}

// ===== 64x128 GEMM tile, bf16 A via global_load_lds. 4 waves: wn = wave id =====
// SCALED: multiply output row r by rsqrt(1+min(cnt[r],ELLCAP)) (symmetric-norm prescale).
template <bool SCALED>
__device__ void gemm64(const unsigned short* __restrict__ A, const unsigned short* __restrict__ Bt,
                       unsigned short* __restrict__ C, const int* __restrict__ cntp,
                       int M, int Ncols, int ldc, int tm, int tn,
                       unsigned short* __restrict__ As, unsigned short* __restrict__ Bs)
{
  const int tid = threadIdx.x;
  const int lane = tid & 63;
  const int wn = tid >> 6;           // 0..3 -> 32-col slice
  const int quad = lane >> 4, l15 = lane & 15;

  const int r0 = tid >> 2, kc = tid & 3;     // r0: 0..63, kc: 0..3
  int ga = tm * 64 + r0;  if (ga > M - 1) ga = M - 1;
  const int gb0 = tn * 128 + r0;
  const int gb1 = tn * 128 + 64 + r0;
  const unsigned short* gA  = A + (size_t)ga * 512 + kc * 8;
  const unsigned short* gB0 = Bt + (size_t)gb0 * 512 + kc * 8;
  const unsigned short* gB1 = Bt + (size_t)gb1 * 512 + kc * 8;
  const int loff  = r0 * 32 + kc * 8;
  const int loff1 = (64 + r0) * 32 + kc * 8;
  const int ABUF = 64 * 32, BBUF = 128 * 32;

  f32x4 acc[4][2];
  #pragma unroll
  for (int i = 0; i < 4; i++)
    #pragma unroll
    for (int j = 0; j < 2; j++) {
      f32x4 z = {0.f, 0.f, 0.f, 0.f};
      acc[i][j] = z;
    }

  load_lds16(gA,  &As[loff]);
  load_lds16(gB0, &Bs[loff]);
  load_lds16(gB1, &Bs[loff1]);
  __syncthreads();

  for (int it = 0; it < 16; ++it) {
    const int ca = (it & 1) * ABUF, cb = (it & 1) * BBUF;
    if (it < 15) {
      const int k1 = (it + 1) * 32;
      const int na = ((it & 1) ^ 1) * ABUF, nb = ((it & 1) ^ 1) * BBUF;
      load_lds16(gA + k1,  &As[na + loff]);
      load_lds16(gB0 + k1, &Bs[nb + loff]);
      load_lds16(gB1 + k1, &Bs[nb + loff1]);
    }
    bf16x8 af[4], bfr[2];
    #pragma unroll
    for (int i = 0; i < 4; i++)
      af[i] = *(const bf16x8*)&As[ca + (i * 16 + l15) * 32 + quad * 8];
    #pragma unroll
    for (int j = 0; j < 2; j++)
      bfr[j] = *(const bf16x8*)&Bs[cb + (wn * 32 + j * 16 + l15) * 32 + quad * 8];
    #pragma unroll
    for (int i = 0; i < 4; i++)
      #pragma unroll
      for (int j = 0; j < 2; j++)
        acc[i][j] = mfma16(af[i], bfr[j], acc[i][j]);
    __syncthreads();
  }

  // C/D layout col=lane&15, row=quad*4+reg  [m89-verified]
  #pragma unroll
  for (int i = 0; i < 4; i++) {
    #pragma unroll
    for (int r = 0; r < 4; r++) {
      const int row = tm * 64 + i * 16 + quad * 4 + r;
      if (row < M) {
        float dv = 1.f;
        if (SCALED) {
          int c = cntp[row]; if (c > ELLCAP) c = ELLCAP;
          dv = rsqrtf((float)(1 + c));
        }
        #pragma unroll
        for (int j = 0; j < 2; j++) {
          const int col = tn * 128 + wn * 32 + j * 16 + l15;
          if (col < Ncols)
            C[(size_t)row * ldc + col] = f2b(acc[i][j][r] * dv);
        }
      }
    }
  }
}

// ===== 64x128 GEMM tile, fp32 A (cvt in staging), bf16 out (unscaled); ldc=512 =====
__device__ void gemm64_f32A(const float* __restrict__ A, const unsigned short* __restrict__ Bt,
                            unsigned short* __restrict__ C, int M, int tm, int tn,
                            unsigned short* __restrict__ As, unsigned short* __restrict__ Bs)
{
  const int tid = threadIdx.x;
  const int lane = tid & 63;
  const int wn = tid >> 6;
  const int quad = lane >> 4, l15 = lane & 15;

  const int r0 = tid >> 2, kc = tid & 3;
  int ga = tm * 64 + r0;  if (ga > M - 1) ga = M - 1;
  const int gb0 = tn * 128 + r0;
  const int gb1 = tn * 128 + 64 + r0;
  const float* gA = A + (size_t)ga * 512 + kc * 8;
  const unsigned short* gB0 = Bt + (size_t)gb0 * 512 + kc * 8;
  const unsigned short* gB1 = Bt + (size_t)gb1 * 512 + kc * 8;
  const int loff  = r0 * 32 + kc * 8;
  const int loff1 = (64 + r0) * 32 + kc * 8;
  const int ABUF = 64 * 32, BBUF = 128 * 32;

  f32x4 acc[4][2];
  #pragma unroll
  for (int i = 0; i < 4; i++)
    #pragma unroll
    for (int j = 0; j < 2; j++) {
      f32x4 z = {0.f, 0.f, 0.f, 0.f};
      acc[i][j] = z;
    }

  {
    float4 a0 = *(const float4*)(gA), a1 = *(const float4*)(gA + 4);
    *(uint4*)&As[loff] = cvt8(a0, a1);
    load_lds16(gB0, &Bs[loff]);
    load_lds16(gB1, &Bs[loff1]);
  }
  __syncthreads();

  for (int it = 0; it < 16; ++it) {
    const int ca = (it & 1) * ABUF, cb = (it & 1) * BBUF;
    const int na = ((it & 1) ^ 1) * ABUF, nb = ((it & 1) ^ 1) * BBUF;
    float4 a0, a1;
    if (it < 15) {
      const int k1 = (it + 1) * 32;
      a0 = *(const float4*)(gA + k1);  a1 = *(const float4*)(gA + k1 + 4);
      load_lds16(gB0 + k1, &Bs[nb + loff]);
      load_lds16(gB1 + k1, &Bs[nb + loff1]);
    }
    bf16x8 af[4], bfr[2];
    #pragma unroll
    for (int i = 0; i < 4; i++)
      af[i] = *(const bf16x8*)&As[ca + (i * 16 + l15) * 32 + quad * 8];
    #pragma unroll
    for (int j = 0; j < 2; j++)
      bfr[j] = *(const bf16x8*)&Bs[cb + (wn * 32 + j * 16 + l15) * 32 + quad * 8];
    #pragma unroll
    for (int i = 0; i < 4; i++)
      #pragma unroll
      for (int j = 0; j < 2; j++)
        acc[i][j] = mfma16(af[i], bfr[j], acc[i][j]);
    if (it < 15) *(uint4*)&As[na + loff] = cvt8(a0, a1);
    __syncthreads();
  }

  #pragma unroll
  for (int i = 0; i < 4; i++) {
    #pragma unroll
    for (int r = 0; r < 4; r++) {
      const int row = tm * 64 + i * 16 + quad * 4 + r;
      if (row < M) {
        #pragma unroll
        for (int j = 0; j < 2; j++) {
          const int col = tn * 128 + wn * 32 + j * 16 + l15;
          C[(size_t)row * 512 + col] = f2b(acc[i][j][r]);
        }
      }
    }
  }
}

// ---- LDS-tiled 64x64 transpose: W fp32 [512][ncols] -> Wt bf16 [.][512] ----
__device__ void wtrans_tile(const float* __restrict__ W, unsigned short* __restrict__ Wt,
                            int ncols, int tr0, int tc0)
{
  __shared__ float tile[64][65];
  const int t = threadIdx.x;
  const int r = t >> 2, c4 = t & 3;
  #pragma unroll
  for (int i = 0; i < 4; i++) {
    int col = c4 * 16 + i * 4;
    int gc = tc0 + col;
    float4 v;
    if (gc + 3 < ncols) {
      v = *(const float4*)&W[(size_t)(tr0 + r) * ncols + gc];
    } else {
      v.x = (gc + 0 < ncols) ? W[(size_t)(tr0 + r) * ncols + gc + 0] : 0.f;
      v.y = (gc + 1 < ncols) ? W[(size_t)(tr0 + r) * ncols + gc + 1] : 0.f;
      v.z = (gc + 2 < ncols) ? W[(size_t)(tr0 + r) * ncols + gc + 2] : 0.f;
      v.w = (gc + 3 < ncols) ? W[(size_t)(tr0 + r) * ncols + gc + 3] : 0.f;
    }
    tile[r][col] = v.x; tile[r][col + 1] = v.y;
    tile[r][col + 2] = v.z; tile[r][col + 3] = v.w;
  }
  __syncthreads();
  const int o = t >> 2;
  #pragma unroll
  for (int i = 0; i < 4; i++) {
    int k = c4 * 16 + i * 4;
    ushort4 u;
    u.x = f2b(tile[k + 0][o]); u.y = f2b(tile[k + 1][o]);
    u.z = f2b(tile[k + 2][o]); u.w = f2b(tile[k + 3][o]);
    *(ushort4*)&Wt[(size_t)(tc0 + o) * 512 + tr0 + k] = u;
  }
}

// ========== K1: prep1 (grid 240) — transposes + W2 cvt + cnt zero ==========
__global__ __launch_bounds__(256)
void prep1(const float* __restrict__ W1, const float* __restrict__ Wc,
           const float* __restrict__ W2, int* __restrict__ cnt,
           unsigned short* __restrict__ W1t, unsigned short* __restrict__ Wct,
           unsigned short* __restrict__ w2b)
{
  if (blockIdx.x < 64) { wtrans_tile(W1, W1t, 512, (blockIdx.x >> 3) * 64, (blockIdx.x & 7) * 64); return; }
  if (blockIdx.x < 80) { int b = blockIdx.x - 64; wtrans_tile(Wc, Wct, 100, (b >> 1) * 64, (b & 1) * 64); return; }
  const int t0 = (blockIdx.x - 80) * 256 + threadIdx.x;
  const int FT = 160 * 256;   // 40960 threads
  const float4* W24 = (const float4*)W2;
  uint4* w2b4 = (uint4*)w2b;
  for (int i = t0; i < 512 * 512 / 8; i += FT)
    w2b4[i] = cvt8(W24[i * 2], W24[i * 2 + 1]);
  if (t0 < NN) cnt[t0] = 0;   // replaces the memset dispatch (NN < FT)
}

// ===== K2: gemm1 (628 tiles, XCD-chunked) + W2Wc fold (8) + bias (1) + ELL build (163) =====
__global__ __launch_bounds__(256)
void gemm1_fold_ell(const float* __restrict__ x, const unsigned short* __restrict__ W1t,
                    unsigned short* __restrict__ B2,
                    const unsigned short* __restrict__ Wct, const unsigned short* __restrict__ w2b,
                    unsigned short* __restrict__ W2WcT,
                    const float* __restrict__ b2, const float* __restrict__ Wc,
                    const float* __restrict__ bc, float* __restrict__ bias2c,
                    const int* __restrict__ src, const int* __restrict__ dst,
                    int* __restrict__ cnt, int* __restrict__ ell, int E)
{
  __shared__ __align__(16) unsigned short As[2 * 64 * 32];
  __shared__ __align__(16) unsigned short Bs[2 * 128 * 32];
  const int b = blockIdx.x;
  if (b < 628) {
    // bijective XCD-chunk swizzle: the 4 tn-tiles sharing one 128KB fp32 A-tile
    // run on the SAME XCD -> A hits L2 instead of 4x HBM refetch.
    const int xcd = b & 7, loc = b >> 3;
    const int base = (xcd < 4) ? xcd * 79 : 316 + (xcd - 4) * 78;
    const int t = base + loc;
    gemm64_f32A(x, W1t, B2, NN, t >> 2, t & 3, As, Bs);
  } else if (b < 636) {               // fold: M=128 -> 2 tm x 4 tn
    const int g = b - 628;
    gemm64<false>(Wct, w2b, W2WcT, nullptr, 128, 512, 512, g >> 2, g & 3, As, Bs);
  } else if (b == 636) {
    const int j = threadIdx.x;
    if (j < 128) {
      float s = 0.f;
      if (j < 100) {
        s = bc[j];
        for (int k = 0; k < 512; k++) s = fmaf(b2[k], Wc[k * 100 + j], s);
      }
      bias2c[j] = s;
    }
  } else {                            // ELL build: 163 blocks stream E edges
    const int t0 = (b - 637) * 256 + threadIdx.x;
    const int FT = 163 * 256;
    for (int e = t0; e < E; e += FT) {
      int s = src[e], d = dst[e];
      int pos = atomicAdd(&cnt[d], 1);
      if (pos < ELLCAP) ell[d * ELLCAP + pos] = s;   // P(overflow) ~ 1e-18 @ Poisson(16)
    }
  }
}

// ========= K3: gather1 — 2 column-halves per node (4 cols/lane, uint2 loads) =========
// Halves each wave's dependent-latency chain and doubles TLP vs full-row waves.
// Traffic unchanged (rows still read in coalesced 512B wave-slices); ELL re-read 2x (L2-hit).
__device__ __forceinline__ void acc4(float* a, uint2 v, float nm) {
  a[0] = fmaf(b2f((unsigned short)(v.x & 0xffffu)), nm, a[0]);
  a[1] = fmaf(b2f((unsigned short)(v.x >> 16)),     nm, a[1]);
  a[2] = fmaf(b2f((unsigned short)(v.y & 0xffffu)), nm, a[2]);
  a[3] = fmaf(b2f((unsigned short)(v.y >> 16)),     nm, a[3]);
}

__global__ __launch_bounds__(256)
void gather1(const unsigned short* __restrict__ h, const int* __restrict__ cnt,
             const int* __restrict__ ell, const float* __restrict__ bias,
             unsigned short* __restrict__ outb, int n)
{
  const int half = blockIdx.x & 1;
  int node = (blockIdx.x >> 1) * 4 + (threadIdx.x >> 6);
  if (node >= n) return;
  const int lane = threadIdx.x & 63;
  const int c4 = half * 256 + lane * 4;    // 4 bf16 cols per lane

  int cd = cnt[node]; if (cd > ELLCAP) cd = ELLCAP;
  const float fd = (float)(1 + cd);
  const float slf = 1.0f / fd;
  uint2 hv = *(const uint2*)&h[(size_t)node * 512 + c4];
  const float4 bb = *(const float4*)&bias[c4];
  float a[4] = {bb.x, bb.y, bb.z, bb.w};
  acc4(a, hv, slf);

  const int* row = ell + node * ELLCAP;
  int j = 0;
  for (; j + 8 <= cd; j += 8) {
    int ss[8]; uint2 vv[8]; float nm[8];
    #pragma unroll
    for (int q = 0; q < 8; q++) ss[q] = row[j + q];
    #pragma unroll
    for (int q = 0; q < 8; q++) vv[q] = *(const uint2*)&h[(size_t)ss[q] * 512 + c4];
    #pragma unroll
    for (int q = 0; q < 8; q++) nm[q] = rsqrtf((float)(1 + cnt[ss[q]]) * fd);
    #pragma unroll
    for (int q = 0; q < 8; q++) acc4(a, vv[q], nm[q]);
  }
  for (; j < cd; ++j) {
    int s = row[j];
    uint2 v = *(const uint2*)&h[(size_t)s * 512 + c4];
    acc4(a, v, rsqrtf((float)(1 + cnt[s]) * fd));
  }
  #pragma unroll
  for (int q = 0; q < 4; q++) a[q] = fmaxf(a[q], 0.f);
  uint2 o;
  o.x = (unsigned int)f2b(a[0]) | ((unsigned int)f2b(a[1]) << 16);
  o.y = (unsigned int)f2b(a[2]) | ((unsigned int)f2b(a[3]) << 16);
  *(uint2*)&outb[(size_t)node * 512 + c4] = o;
}

// ===== K4: gemm2c: Z' = dinv * (B1 @ W2WcT^T) (bf16, 128 cols); 157 tiles =====
__global__ __launch_bounds__(256)
void gemm2c(const unsigned short* __restrict__ B1, const unsigned short* __restrict__ W2WcT,
            unsigned short* __restrict__ Z, const int* __restrict__ cnt)
{
  __shared__ __align__(16) unsigned short As[2 * 64 * 32];
  __shared__ __align__(16) unsigned short Bs[2 * 128 * 32];
  gemm64<true>(B1, W2WcT, Z, cnt, NN, 128, 128, blockIdx.x, 0, As, Bs);
}

// ========= K5: gather2c (prescaled Z rows -> pure row-sum) =========
__global__ __launch_bounds__(256)
void gather2c(const unsigned short* __restrict__ Z, const int* __restrict__ cnt,
              const int* __restrict__ ell, const float* __restrict__ bias2c,
              float* __restrict__ out, int n)
{
  int node = blockIdx.x * 4 + (threadIdx.x >> 6);
  if (node >= n) return;
  const int lane = threadIdx.x & 63;
  const int c2 = lane * 2;

  int cd = cnt[node]; if (cd > ELLCAP) cd = ELLCAP;
  const float dinv = rsqrtf((float)(1 + cd));
  unsigned int hv = *(const unsigned int*)&Z[(size_t)node * 128 + c2];
  float a0 = b2f((unsigned short)(hv & 0xffffu));
  float a1 = b2f((unsigned short)(hv >> 16));

  const int* row = ell + node * ELLCAP;
  int j = 0;
  for (; j + 8 <= cd; j += 8) {
    int ss[8]; unsigned int vv[8];
    #pragma unroll
    for (int q = 0; q < 8; q++) ss[q] = row[j + q];
    #pragma unroll
    for (int q = 0; q < 8; q++) vv[q] = *(const unsigned int*)&Z[(size_t)ss[q] * 128 + c2];
    #pragma unroll
    for (int q = 0; q < 8; q++) {
      a0 += b2f((unsigned short)(vv[q] & 0xffffu));
      a1 += b2f((unsigned short)(vv[q] >> 16));
    }
  }
  for (; j < cd; ++j) {
    int s = row[j];
    unsigned int v = *(const unsigned int*)&Z[(size_t)s * 128 + c2];
    a0 += b2f((unsigned short)(v & 0xffffu));
    a1 += b2f((unsigned short)(v >> 16));
  }
  if (c2 < 100) {
    const float2 bb = *(const float2*)&bias2c[c2];
    *(float2*)&out[(size_t)node * 100 + c2] =
        make_float2(fmaf(a0, dinv, bb.x), fmaf(a1, dinv, bb.y));
  }
}

extern "C" void kernel_launch(void* const* d_in, const int* in_sizes, int n_in,
                              void* d_out, int out_size, void* d_ws, size_t ws_size,
                              hipStream_t stream) {
  const float* x  = (const float*)d_in[0];
  const int*   ei = (const int*)d_in[1];
  const float* W1 = (const float*)d_in[2];
  const float* b1 = (const float*)d_in[3];
  const float* W2 = (const float*)d_in[4];
  const float* b2 = (const float*)d_in[5];
  const float* Wc = (const float*)d_in[6];
  const float* bc = (const float*)d_in[7];
  float* out = (float*)d_out;

  const int n = NN;
  const int E = in_sizes[1] / 2;
  const int* src = ei;
  const int* dst = ei + E;

  // workspace (~26 MB)
  char* w = (char*)d_ws;
  int* cnt = (int*)w;                       w += ((n * 4 + 255) / 256) * 256;
  int* ell = (int*)w;                       w += ((n * ELLCAP * 4 + 255) / 256) * 256;
  float* bias2c = (float*)w;                w += 512;
  unsigned short* W1t = (unsigned short*)w; w += 512 * 512 * 2;
  unsigned short* Wct = (unsigned short*)w; w += 128 * 512 * 2;
  unsigned short* w2b = (unsigned short*)w; w += 512 * 512 * 2;
  unsigned short* W2WcT = (unsigned short*)w; w += 128 * 512 * 2;
  unsigned short* B1  = (unsigned short*)w; w += (size_t)n * 512 * 2;
  unsigned short* B2  = (unsigned short*)w; w += (size_t)n * 512 * 2;
  unsigned short* Z   = (unsigned short*)w; w += (size_t)n * 128 * 2;

  const int nb_g = (n + 3) / 4;

  prep1<<<240, 256, 0, stream>>>(W1, Wc, W2, cnt, W1t, Wct, w2b);
  gemm1_fold_ell<<<800, 256, 0, stream>>>(x, W1t, B2, Wct, w2b, W2WcT,
                                          b2, Wc, bc, bias2c, src, dst, cnt, ell, E);
  gather1<<<nb_g * 2, 256, 0, stream>>>(B2, cnt, ell, b1, B1, n);
  gemm2c<<<157, 256, 0, stream>>>(B1, W2WcT, Z, cnt);
  gather2c<<<nb_g, 256, 0, stream>>>(Z, cnt, ell, bias2c, out, n);
}